// Round 11
// baseline (1044.970 us; speedup 1.0000x reference)
//
#include <hip/hip_runtime.h>

#define NN 100000
#define NE 1600000
#define NPB 128                 // nodes per bucket
#define NBK 782                 // ceil(NN/128)
#define EPB 16384               // edges per partition block

// workspace word offsets (max end ~14,501,692 words = 58.0 MB, same as prior rounds)
#define OFF_H      0            // h f32 [N,64] (6.4M words)
#define OFF_YL     6400000      // yl bf16 [N,64] (3.2M words); zl bf16 [N,16] overlays after agg1b
#define OFF_YR     9600000      // yr bf16 [N,64] (3.2M words); zr f32 [N,16] overlays after agg1b
#define OFF_EBUF   12800000     // packed edges int x 1.6M
#define OFF_HIST   14400000     // 100,000 i (degrees; live to the end)
#define OFF_BSTART 14500000     // 782 i
#define OFF_BCUR   14500782     // 782 i
#define OFF_BNACC  14501564     // 128 f

typedef __attribute__((ext_vector_type(8))) short bf16x8;
typedef __attribute__((ext_vector_type(4))) float f32x4;

__device__ __forceinline__ ushort f2bf(float f) {   // RNE f32 -> bf16
  unsigned u = __float_as_uint(f);
  u += 0x7fffu + ((u >> 16) & 1);
  return (ushort)(u >> 16);
}
#define BFLO(u) __uint_as_float(((u) & 0xffffu) << 16)
#define BFHI(u) __uint_as_float((u) & 0xffff0000u)

// ---------------------------------------------------------------------------
// degree histogram (by dst)
// ---------------------------------------------------------------------------
__global__ __launch_bounds__(256) void k_hist(const int* __restrict__ ei,
                                              int* __restrict__ hist) {
  int e = blockIdx.x * 256 + threadIdx.x;
  if (e < NE) atomicAdd(&hist[ei[NE + e]], 1);
}

// ---------------------------------------------------------------------------
// per-bucket totals from hist + exclusive scan -> bstart, bcur (one block)
// ---------------------------------------------------------------------------
__global__ __launch_bounds__(1024) void k_bprep(const int* __restrict__ hist,
                                                int* __restrict__ bstart,
                                                int* __restrict__ bcur) {
  __shared__ int sd[1024];
  int t = threadIdx.x;
  int acc = 0;
  if (t < NBK) {
    int base = t << 7;
    int nnode = min(NPB, NN - base);
    if (nnode == NPB) {
      const int4* hp = (const int4*)(hist + base);
#pragma unroll 8
      for (int i = 0; i < 32; ++i) { int4 v = hp[i]; acc += v.x + v.y + v.z + v.w; }
    } else {
      for (int i = 0; i < nnode; ++i) acc += hist[base + i];
    }
  }
  sd[t] = acc;
  __syncthreads();
  for (int off = 1; off < 1024; off <<= 1) {
    int v = (t >= off) ? sd[t - off] : 0;
    __syncthreads();
    sd[t] += v;
    __syncthreads();
  }
  if (t < NBK) { int s = sd[t] - acc; bstart[t] = s; bcur[t] = s; }
}

// ---------------------------------------------------------------------------
// partition edges into bucket-contiguous regions, packed (src<<7 | dst&127)
// ---------------------------------------------------------------------------
__global__ __launch_bounds__(256) void k_part(const int* __restrict__ ei,
                                              int* __restrict__ bcur,
                                              int* __restrict__ ebuf) {
  __shared__ int cnt[NBK], gstart[NBK], cur[NBK];
  int e0 = blockIdx.x * EPB;
  int e1 = min(e0 + EPB, NE);
  for (int i = threadIdx.x; i < NBK; i += 256) cnt[i] = 0;
  __syncthreads();
  for (int e = e0 + threadIdx.x; e < e1; e += 256)
    atomicAdd(&cnt[ei[NE + e] >> 7], 1);
  __syncthreads();
  for (int b = threadIdx.x; b < NBK; b += 256) {
    int c = cnt[b];
    gstart[b] = c ? atomicAdd(&bcur[b], c) : 0;
    cur[b] = 0;
  }
  __syncthreads();
  for (int e = e0 + threadIdx.x; e < e1; e += 256) {
    int s = ei[e], t = ei[NE + e];
    int b = t >> 7;
    int r = atomicAdd(&cur[b], 1);
    ebuf[gstart[b] + r] = (s << 7) | (t & 127);
  }
}

// ---------------------------------------------------------------------------
// k_gemm12 (MFMA): yl = x@W1l^T, yr = x@W1r^T (both bf16), x staged once.
// ---------------------------------------------------------------------------
__global__ __launch_bounds__(256) void k_gemm12(const float* __restrict__ x,
                                                const float* __restrict__ W1l,
                                                const float* __restrict__ W1r,
                                                ushort* __restrict__ yl,
                                                ushort* __restrict__ yr) {
  __shared__ ushort xs[64 * 136];
  __shared__ ushort wss[128 * 136];
  const int tid = threadIdx.x;
  const int n0 = blockIdx.x * 64;

  for (int i = tid; i < 64 * 32; i += 256) {
    int r = i >> 5, c = i & 31;
    int n = n0 + r;
    float4 v = (n < NN) ? *(const float4*)&x[(size_t)n * 128 + c * 4]
                        : make_float4(0.f, 0.f, 0.f, 0.f);
    *(ushort4*)&xs[r * 136 + c * 4] = make_ushort4(f2bf(v.x), f2bf(v.y), f2bf(v.z), f2bf(v.w));
  }
  for (int i = tid; i < 128 * 32; i += 256) {
    int r = i >> 5, c = i & 31;
    const float* src = (r < 64) ? &W1l[r * 128 + c * 4] : &W1r[(r - 64) * 128 + c * 4];
    float4 v = *(const float4*)src;
    *(ushort4*)&wss[r * 136 + c * 4] = make_ushort4(f2bf(v.x), f2bf(v.y), f2bf(v.z), f2bf(v.w));
  }
  __syncthreads();

  const int w = tid >> 6, l = tid & 63;
  const int col = l & 15, kb = l >> 4;

  f32x4 acc[4][2];
#pragma unroll
  for (int nt = 0; nt < 4; ++nt)
#pragma unroll
    for (int ot = 0; ot < 2; ++ot) acc[nt][ot] = (f32x4){0.f, 0.f, 0.f, 0.f};

#pragma unroll
  for (int kc = 0; kc < 4; ++kc) {
    int koff = kc * 32 + kb * 8;
    bf16x8 a[4], b[2];
#pragma unroll
    for (int nt = 0; nt < 4; ++nt)
      a[nt] = *(const bf16x8*)&xs[(nt * 16 + col) * 136 + koff];
#pragma unroll
    for (int ot = 0; ot < 2; ++ot)
      b[ot] = *(const bf16x8*)&wss[((w * 2 + ot) * 16 + col) * 136 + koff];
#pragma unroll
    for (int nt = 0; nt < 4; ++nt)
#pragma unroll
      for (int ot = 0; ot < 2; ++ot)
        acc[nt][ot] = __builtin_amdgcn_mfma_f32_16x16x32_bf16(a[nt], b[ot], acc[nt][ot], 0, 0, 0);
  }

#pragma unroll
  for (int nt = 0; nt < 4; ++nt)
#pragma unroll
    for (int ot = 0; ot < 2; ++ot) {
      int outc = (w * 2 + ot) * 16 + col;
#pragma unroll
      for (int r = 0; r < 4; ++r) {
        int n = n0 + nt * 16 + kb * 4 + r;
        if (n < NN) {
          ushort v = f2bf(acc[nt][ot][r]);
          if (outc < 64) yl[(size_t)n * 64 + outc] = v;
          else           yr[(size_t)n * 64 + (outc - 64)] = v;
        }
      }
    }
}

// ---------------------------------------------------------------------------
// k_agg1b: one block per 128-node bucket. Stream packed edges; independent
// uint4 gathers of yl[src] (8 lanes/edge); ds_add into padded LDS sums.
// Finalize: h = sums/deg + b1 + yr, + BN partials.
// ---------------------------------------------------------------------------
__global__ __launch_bounds__(512) void k_agg1b(const int* __restrict__ ebuf,
                                               const int* __restrict__ bstart,
                                               const int* __restrict__ bcur,
                                               const int* __restrict__ hist,
                                               const ushort* __restrict__ yl,
                                               const ushort* __restrict__ yr,
                                               const float* __restrict__ b1,
                                               float* __restrict__ h,
                                               float* __restrict__ bnacc) {
  __shared__ float sums[128 * 68];   // pad 68 -> 2-way banked ds_add
  __shared__ float bnS[64], bnQ[64];
  const int tid = threadIdx.x;
  const int b = blockIdx.x;
  const int node0 = b << 7;

  for (int i = tid; i < 128 * 68; i += 512) sums[i] = 0.f;
  if (tid < 64) { bnS[tid] = 0.f; bnQ[tid] = 0.f; }
  __syncthreads();

  const int f8 = tid & 7;            // feats f8*8 .. +7
  const int kend = bcur[b];
  for (int k = bstart[b] + (tid >> 3); k < kend; k += 64) {
    int e = ebuf[k];
    int src = e >> 7, dl = e & 127;
    uint4 v = *(const uint4*)&yl[(size_t)src * 64 + f8 * 8];
    float* srow = &sums[dl * 68 + f8 * 8];
    atomicAdd(&srow[0], BFLO(v.x)); atomicAdd(&srow[1], BFHI(v.x));
    atomicAdd(&srow[2], BFLO(v.y)); atomicAdd(&srow[3], BFHI(v.y));
    atomicAdd(&srow[4], BFLO(v.z)); atomicAdd(&srow[5], BFHI(v.z));
    atomicAdd(&srow[6], BFLO(v.w)); atomicAdd(&srow[7], BFHI(v.w));
  }
  __syncthreads();

  const int nnode = min(NPB, NN - node0);
  const int fq = tid & 15;           // feats fq*4 .. +3
  float s0 = 0.f, s1 = 0.f, s2 = 0.f, s3 = 0.f;
  float q0 = 0.f, q1 = 0.f, q2 = 0.f, q3 = 0.f;
  const float4 bv = *(const float4*)&b1[fq * 4];
#pragma unroll
  for (int p = 0; p < 4; ++p) {
    int dl = p * 32 + (tid >> 4);
    if (dl < nnode) {
      int node = node0 + dl;
      float invc = 1.0f / fmaxf((float)hist[node], 1.0f);
      uint2 rv = *(const uint2*)&yr[(size_t)node * 64 + fq * 4];
      const float* srow = &sums[dl * 68 + fq * 4];
      float h0 = srow[0] * invc + bv.x + BFLO(rv.x);
      float h1 = srow[1] * invc + bv.y + BFHI(rv.x);
      float h2 = srow[2] * invc + bv.z + BFLO(rv.y);
      float h3 = srow[3] * invc + bv.w + BFHI(rv.y);
      *(float4*)&h[(size_t)node * 64 + fq * 4] = make_float4(h0, h1, h2, h3);
      s0 += h0; s1 += h1; s2 += h2; s3 += h3;
      q0 += h0 * h0; q1 += h1 * h1; q2 += h2 * h2; q3 += h3 * h3;
    }
  }
  atomicAdd(&bnS[fq * 4 + 0], s0); atomicAdd(&bnQ[fq * 4 + 0], q0);
  atomicAdd(&bnS[fq * 4 + 1], s1); atomicAdd(&bnQ[fq * 4 + 1], q1);
  atomicAdd(&bnS[fq * 4 + 2], s2); atomicAdd(&bnQ[fq * 4 + 2], q2);
  atomicAdd(&bnS[fq * 4 + 3], s3); atomicAdd(&bnQ[fq * 4 + 3], q3);
  __syncthreads();
  if (tid < 64) {
    atomicAdd(&bnacc[tid], bnS[tid]);
    atomicAdd(&bnacc[64 + tid], bnQ[tid]);
  }
}

// ---------------------------------------------------------------------------
// k_layer2m (MFMA, BN-finalize fused): h' = relu(bn(h));
// zl = h'@W2_l^T (bf16); zr = h'@W2_r^T + b2 (f32)
// ---------------------------------------------------------------------------
__global__ __launch_bounds__(256) void k_layer2m(const float* __restrict__ h,
                                                 const float* __restrict__ W2l,
                                                 const float* __restrict__ W2r,
                                                 const float* __restrict__ b2,
                                                 const float* __restrict__ bnacc,
                                                 const float* __restrict__ gamma,
                                                 const float* __restrict__ beta,
                                                 ushort* __restrict__ zl,
                                                 float* __restrict__ zr) {
  __shared__ ushort hs[64 * 72];
  __shared__ ushort wss[32 * 72];
  __shared__ float sc[64], sh[64];
  const int tid = threadIdx.x;
  const int n0 = blockIdx.x * 64;

  if (tid < 64) {
    float mean = bnacc[tid] * (1.0f / NN);
    float var = bnacc[64 + tid] * (1.0f / NN) - mean * mean;
    float scv = gamma[tid] * rsqrtf(var + 1e-5f);
    sc[tid] = scv;
    sh[tid] = beta[tid] - mean * scv;
  }
  for (int i = tid; i < 32 * 16; i += 256) {
    int r = i >> 4, c = i & 15;
    const float* src = (r < 16) ? &W2l[r * 64 + c * 4] : &W2r[(r - 16) * 64 + c * 4];
    float4 v = *(const float4*)src;
    *(ushort4*)&wss[r * 72 + c * 4] = make_ushort4(f2bf(v.x), f2bf(v.y), f2bf(v.z), f2bf(v.w));
  }
  __syncthreads();

  for (int i = tid; i < 64 * 16; i += 256) {
    int r = i >> 4, c = i & 15;
    int n = n0 + r;
    float4 v = (n < NN) ? *(const float4*)&h[(size_t)n * 64 + c * 4]
                        : make_float4(0.f, 0.f, 0.f, 0.f);
    float4 o;
    o.x = fmaxf(v.x * sc[c * 4 + 0] + sh[c * 4 + 0], 0.f);
    o.y = fmaxf(v.y * sc[c * 4 + 1] + sh[c * 4 + 1], 0.f);
    o.z = fmaxf(v.z * sc[c * 4 + 2] + sh[c * 4 + 2], 0.f);
    o.w = fmaxf(v.w * sc[c * 4 + 3] + sh[c * 4 + 3], 0.f);
    *(ushort4*)&hs[r * 72 + c * 4] = make_ushort4(f2bf(o.x), f2bf(o.y), f2bf(o.z), f2bf(o.w));
  }
  __syncthreads();

  const int w = tid >> 6, l = tid & 63;
  const int col = l & 15, kb = l >> 4;

  f32x4 acc[2] = {(f32x4){0.f, 0.f, 0.f, 0.f}, (f32x4){0.f, 0.f, 0.f, 0.f}};
#pragma unroll
  for (int kc = 0; kc < 2; ++kc) {
    int koff = kc * 32 + kb * 8;
    bf16x8 a = *(const bf16x8*)&hs[(w * 16 + col) * 72 + koff];
    bf16x8 b0 = *(const bf16x8*)&wss[col * 72 + koff];
    bf16x8 b1v = *(const bf16x8*)&wss[(16 + col) * 72 + koff];
    acc[0] = __builtin_amdgcn_mfma_f32_16x16x32_bf16(a, b0, acc[0], 0, 0, 0);
    acc[1] = __builtin_amdgcn_mfma_f32_16x16x32_bf16(a, b1v, acc[1], 0, 0, 0);
  }

#pragma unroll
  for (int r = 0; r < 4; ++r) {
    int n = n0 + w * 16 + kb * 4 + r;
    if (n < NN) {
      zl[(size_t)n * 16 + col] = f2bf(acc[0][r]);
      zr[(size_t)n * 16 + col] = acc[1][r] + b2[col];
    }
  }
}

// ---------------------------------------------------------------------------
// k_agg2b: same bucket-streaming for layer 2; out = sums/deg + zr.
// ---------------------------------------------------------------------------
__global__ __launch_bounds__(256) void k_agg2b(const int* __restrict__ ebuf,
                                               const int* __restrict__ bstart,
                                               const int* __restrict__ bcur,
                                               const int* __restrict__ hist,
                                               const ushort* __restrict__ zl,
                                               const float* __restrict__ zr,
                                               float* __restrict__ out) {
  __shared__ float sums[128 * 17];   // pad 17 -> spread banks
  const int tid = threadIdx.x;
  const int b = blockIdx.x;
  const int node0 = b << 7;

  for (int i = tid; i < 128 * 17; i += 256) sums[i] = 0.f;
  __syncthreads();

  const int f = tid & 7;             // feats f*2, f*2+1
  const int kend = bcur[b];
  for (int k = bstart[b] + (tid >> 3); k < kend; k += 32) {
    int e = ebuf[k];
    int src = e >> 7, dl = e & 127;
    unsigned v = *(const unsigned*)&zl[(size_t)src * 16 + f * 2];
    atomicAdd(&sums[dl * 17 + f * 2],     BFLO(v));
    atomicAdd(&sums[dl * 17 + f * 2 + 1], BFHI(v));
  }
  __syncthreads();

  const int nnode = min(NPB, NN - node0);
  const int fq = tid & 3;            // feats fq*4 .. +3
#pragma unroll
  for (int p = 0; p < 2; ++p) {
    int dl = p * 64 + (tid >> 2);
    if (dl < nnode) {
      int node = node0 + dl;
      float invc = 1.0f / fmaxf((float)hist[node], 1.0f);
      size_t base = (size_t)node * 16 + fq * 4;
      float4 rv = *(const float4*)&zr[base];
      const float* srow = &sums[dl * 17 + fq * 4];
      *(float4*)&out[base] = make_float4(srow[0] * invc + rv.x, srow[1] * invc + rv.y,
                                         srow[2] * invc + rv.z, srow[3] * invc + rv.w);
    }
  }
}

// ---------------------------------------------------------------------------
extern "C" void kernel_launch(void* const* d_in, const int* in_sizes, int n_in,
                              void* d_out, int out_size, void* d_ws, size_t ws_size,
                              hipStream_t stream) {
  const float* x     = (const float*)d_in[0];
  const int*   ei    = (const int*)d_in[1];
  const float* W1l   = (const float*)d_in[2];
  const float* b1    = (const float*)d_in[3];
  const float* W1r   = (const float*)d_in[4];
  const float* gamma = (const float*)d_in[5];
  const float* beta  = (const float*)d_in[6];
  const float* W2l   = (const float*)d_in[7];
  const float* b2    = (const float*)d_in[8];
  const float* W2r   = (const float*)d_in[9];
  float* out = (float*)d_out;
  float* ws  = (float*)d_ws;

  float*  hbuf   = ws + OFF_H;
  ushort* yl     = (ushort*)(ws + OFF_YL);
  ushort* yr     = (ushort*)(ws + OFF_YR);
  ushort* zl     = (ushort*)(ws + OFF_YL);   // overlays yl (dead after agg1b)
  float*  zr     = ws + OFF_YR;              // overlays yr (dead after agg1b)
  int*    ebuf   = (int*)(ws + OFF_EBUF);
  int*    hist   = (int*)(ws + OFF_HIST);
  int*    bstart = (int*)(ws + OFF_BSTART);
  int*    bcur   = (int*)(ws + OFF_BCUR);
  float*  bnacc  = ws + OFF_BNACC;

  hipMemsetAsync(hist, 0, NN * sizeof(int), stream);
  hipMemsetAsync(bnacc, 0, 128 * sizeof(float), stream);

  const int ntiles = (NN + 63) / 64;         // 1563
  k_hist<<<(NE + 255) / 256, 256, 0, stream>>>(ei, hist);
  k_bprep<<<1, 1024, 0, stream>>>(hist, bstart, bcur);
  k_part<<<(NE + EPB - 1) / EPB, 256, 0, stream>>>(ei, bcur, ebuf);
  k_gemm12<<<ntiles, 256, 0, stream>>>(x, W1l, W1r, yl, yr);
  k_agg1b<<<NBK, 512, 0, stream>>>(ebuf, bstart, bcur, hist, yl, yr, b1, hbuf, bnacc);
  k_layer2m<<<ntiles, 256, 0, stream>>>(hbuf, W2l, W2r, b2, bnacc, gamma, beta, zl, zr);
  k_agg2b<<<NBK, 256, 0, stream>>>(ebuf, bstart, bcur, hist, zl, zr, out);
}

// Round 12
// 255.514 us; speedup vs baseline: 4.0897x; 4.0897x over previous
//
#include <hip/hip_runtime.h>

#define NN 100000
#define NE 1600000
#define NPB 128                 // nodes per bucket
#define NBK 782                 // ceil(NN/128)
#define EPB 16384               // edges per partition block
#define CAP 4096                // max edges per bucket (mean 2048, sigma 45 -> 45-sigma margin)

// workspace word offsets
#define OFF_H      0            // h f32 [N,64] (6.4M words)
#define OFF_YL     6400000      // yl bf16 [N,64] (3.2M words); zl bf16 [N,16] overlays after agg1c
#define OFF_YR     9600000      // yr bf16 [N,64] (3.2M words); zr f32 [N,16] overlays after agg1c
#define OFF_EBUF   12800000     // packed edges int x 1.6M (raw -> sorted src in place)
#define OFF_HIST   14400000     // 100,000 i (degrees; live to the end)
#define OFF_BSTART 14500000     // 782 i
#define OFF_BCUR   14500782     // 782 i
#define OFF_BNACC  14501564     // 128 f

typedef __attribute__((ext_vector_type(8))) short bf16x8;
typedef __attribute__((ext_vector_type(4))) float f32x4;

__device__ __forceinline__ ushort f2bf(float f) {   // RNE f32 -> bf16
  unsigned u = __float_as_uint(f);
  u += 0x7fffu + ((u >> 16) & 1);
  return (ushort)(u >> 16);
}
#define BFLO(u) __uint_as_float(((u) & 0xffffu) << 16)
#define BFHI(u) __uint_as_float((u) & 0xffff0000u)

// ---------------------------------------------------------------------------
// degree histogram (by dst)
// ---------------------------------------------------------------------------
__global__ __launch_bounds__(256) void k_hist(const int* __restrict__ ei,
                                              int* __restrict__ hist) {
  int e = blockIdx.x * 256 + threadIdx.x;
  if (e < NE) atomicAdd(&hist[ei[NE + e]], 1);
}

// ---------------------------------------------------------------------------
// per-bucket totals from hist + exclusive scan -> bstart, bcur (one block)
// ---------------------------------------------------------------------------
__global__ __launch_bounds__(1024) void k_bprep(const int* __restrict__ hist,
                                                int* __restrict__ bstart,
                                                int* __restrict__ bcur) {
  __shared__ int sd[1024];
  int t = threadIdx.x;
  int acc = 0;
  if (t < NBK) {
    int base = t << 7;
    int nnode = min(NPB, NN - base);
    if (nnode == NPB) {
      const int4* hp = (const int4*)(hist + base);
#pragma unroll 8
      for (int i = 0; i < 32; ++i) { int4 v = hp[i]; acc += v.x + v.y + v.z + v.w; }
    } else {
      for (int i = 0; i < nnode; ++i) acc += hist[base + i];
    }
  }
  sd[t] = acc;
  __syncthreads();
  for (int off = 1; off < 1024; off <<= 1) {
    int v = (t >= off) ? sd[t - off] : 0;
    __syncthreads();
    sd[t] += v;
    __syncthreads();
  }
  if (t < NBK) { int s = sd[t] - acc; bstart[t] = s; bcur[t] = s; }
}

// ---------------------------------------------------------------------------
// partition edges into bucket-contiguous regions, packed (src<<7 | dst&127)
// ---------------------------------------------------------------------------
__global__ __launch_bounds__(256) void k_part(const int* __restrict__ ei,
                                              int* __restrict__ bcur,
                                              int* __restrict__ ebuf) {
  __shared__ int cnt[NBK], gstart[NBK], cur[NBK];
  int e0 = blockIdx.x * EPB;
  int e1 = min(e0 + EPB, NE);
  for (int i = threadIdx.x; i < NBK; i += 256) cnt[i] = 0;
  __syncthreads();
  for (int e = e0 + threadIdx.x; e < e1; e += 256)
    atomicAdd(&cnt[ei[NE + e] >> 7], 1);
  __syncthreads();
  for (int b = threadIdx.x; b < NBK; b += 256) {
    int c = cnt[b];
    gstart[b] = c ? atomicAdd(&bcur[b], c) : 0;
    cur[b] = 0;
  }
  __syncthreads();
  for (int e = e0 + threadIdx.x; e < e1; e += 256) {
    int s = ei[e], t = ei[NE + e];
    int b = t >> 7;
    int r = atomicAdd(&cur[b], 1);
    ebuf[gstart[b] + r] = (s << 7) | (t & 127);
  }
}

// ---------------------------------------------------------------------------
// k_gemm12 (MFMA): yl = x@W1l^T, yr = x@W1r^T (both bf16), x staged once.
// ---------------------------------------------------------------------------
__global__ __launch_bounds__(256) void k_gemm12(const float* __restrict__ x,
                                                const float* __restrict__ W1l,
                                                const float* __restrict__ W1r,
                                                ushort* __restrict__ yl,
                                                ushort* __restrict__ yr) {
  __shared__ ushort xs[64 * 136];
  __shared__ ushort wss[128 * 136];
  const int tid = threadIdx.x;
  const int n0 = blockIdx.x * 64;

  for (int i = tid; i < 64 * 32; i += 256) {
    int r = i >> 5, c = i & 31;
    int n = n0 + r;
    float4 v = (n < NN) ? *(const float4*)&x[(size_t)n * 128 + c * 4]
                        : make_float4(0.f, 0.f, 0.f, 0.f);
    *(ushort4*)&xs[r * 136 + c * 4] = make_ushort4(f2bf(v.x), f2bf(v.y), f2bf(v.z), f2bf(v.w));
  }
  for (int i = tid; i < 128 * 32; i += 256) {
    int r = i >> 5, c = i & 31;
    const float* src = (r < 64) ? &W1l[r * 128 + c * 4] : &W1r[(r - 64) * 128 + c * 4];
    float4 v = *(const float4*)src;
    *(ushort4*)&wss[r * 136 + c * 4] = make_ushort4(f2bf(v.x), f2bf(v.y), f2bf(v.z), f2bf(v.w));
  }
  __syncthreads();

  const int w = tid >> 6, l = tid & 63;
  const int col = l & 15, kb = l >> 4;

  f32x4 acc[4][2];
#pragma unroll
  for (int nt = 0; nt < 4; ++nt)
#pragma unroll
    for (int ot = 0; ot < 2; ++ot) acc[nt][ot] = (f32x4){0.f, 0.f, 0.f, 0.f};

#pragma unroll
  for (int kc = 0; kc < 4; ++kc) {
    int koff = kc * 32 + kb * 8;
    bf16x8 a[4], b[2];
#pragma unroll
    for (int nt = 0; nt < 4; ++nt)
      a[nt] = *(const bf16x8*)&xs[(nt * 16 + col) * 136 + koff];
#pragma unroll
    for (int ot = 0; ot < 2; ++ot)
      b[ot] = *(const bf16x8*)&wss[((w * 2 + ot) * 16 + col) * 136 + koff];
#pragma unroll
    for (int nt = 0; nt < 4; ++nt)
#pragma unroll
      for (int ot = 0; ot < 2; ++ot)
        acc[nt][ot] = __builtin_amdgcn_mfma_f32_16x16x32_bf16(a[nt], b[ot], acc[nt][ot], 0, 0, 0);
  }

#pragma unroll
  for (int nt = 0; nt < 4; ++nt)
#pragma unroll
    for (int ot = 0; ot < 2; ++ot) {
      int outc = (w * 2 + ot) * 16 + col;
#pragma unroll
      for (int r = 0; r < 4; ++r) {
        int n = n0 + nt * 16 + kb * 4 + r;
        if (n < NN) {
          ushort v = f2bf(acc[nt][ot][r]);
          if (outc < 64) yl[(size_t)n * 64 + outc] = v;
          else           yr[(size_t)n * 64 + (outc - 64)] = v;
        }
      }
    }
}

// ---------------------------------------------------------------------------
// k_agg1c: per bucket — counting-sort edges by dst in LDS (int atomics only),
// then 8-lane groups accumulate each node's contiguous edge list in REGISTERS.
// Writes sorted src list back to ebuf (reused by k_agg2c).
// h = sums/deg + b1 + yr; BN partials via shfl reduce (no float atomics).
// ---------------------------------------------------------------------------
__global__ __launch_bounds__(512) void k_agg1c(int* __restrict__ ebuf,
                                               const int* __restrict__ bstart,
                                               const int* __restrict__ bcur,
                                               const int* __restrict__ hist,
                                               const ushort* __restrict__ yl,
                                               const ushort* __restrict__ yr,
                                               const float* __restrict__ b1,
                                               float* __restrict__ h,
                                               float* __restrict__ bnacc) {
  __shared__ int raw[CAP];
  __shared__ int srt[CAP];
  __shared__ int sd[128], deg[128], offx[128], cursor[128];
  __shared__ float bnWs[8][64], bnWq[8][64];
  const int tid = threadIdx.x;
  const int b = blockIdx.x;
  const int node0 = b << 7;
  const int nnode = min(NPB, NN - node0);
  const int kstart = bstart[b];
  const int T = bcur[b] - kstart;

  // phase 1: stage raw edges + degree scan
  for (int i = tid; i < T; i += 512) raw[i] = ebuf[kstart + i];
  if (tid < 128) {
    int d = (tid < nnode) ? hist[node0 + tid] : 0;
    deg[tid] = d;
    sd[tid] = d;
  }
  __syncthreads();
  for (int o = 1; o < 128; o <<= 1) {
    int v = (tid < 128 && tid >= o) ? sd[tid - o] : 0;
    __syncthreads();
    if (tid < 128) sd[tid] += v;
    __syncthreads();
  }
  if (tid < 128) {
    int s = sd[tid] - deg[tid];
    offx[tid] = s;
    cursor[tid] = s;
  }
  __syncthreads();

  // phase 2: counting sort by dst (native int LDS atomics)
  for (int i = tid; i < T; i += 512) {
    int e = raw[i];
    int slot = atomicAdd(&cursor[e & 127], 1);
    srt[slot] = e >> 7;
  }
  __syncthreads();

  // phase 3: write sorted src list back to global (for agg2c)
  for (int i = tid; i < T; i += 512) ebuf[kstart + i] = srt[i];

  // phase 4: register accumulation, 8-lane group per node
  const int g = tid >> 3, f8 = tid & 7;
  float s[8] = {}, q[8] = {};
#pragma unroll
  for (int rep = 0; rep < 2; ++rep) {
    int dl = g + rep * 64;
    if (dl < nnode) {
      int st = offx[dl], d = deg[dl];
      float a[8] = {};
      int k = st, ke = st + d;
      for (; k + 1 < ke; k += 2) {
        int s0 = srt[k], s1 = srt[k + 1];
        uint4 v0 = *(const uint4*)&yl[(size_t)s0 * 64 + f8 * 8];
        uint4 v1 = *(const uint4*)&yl[(size_t)s1 * 64 + f8 * 8];
        a[0] += BFLO(v0.x) + BFLO(v1.x); a[1] += BFHI(v0.x) + BFHI(v1.x);
        a[2] += BFLO(v0.y) + BFLO(v1.y); a[3] += BFHI(v0.y) + BFHI(v1.y);
        a[4] += BFLO(v0.z) + BFLO(v1.z); a[5] += BFHI(v0.z) + BFHI(v1.z);
        a[6] += BFLO(v0.w) + BFLO(v1.w); a[7] += BFHI(v0.w) + BFHI(v1.w);
      }
      if (k < ke) {
        int s0 = srt[k];
        uint4 v0 = *(const uint4*)&yl[(size_t)s0 * 64 + f8 * 8];
        a[0] += BFLO(v0.x); a[1] += BFHI(v0.x);
        a[2] += BFLO(v0.y); a[3] += BFHI(v0.y);
        a[4] += BFLO(v0.z); a[5] += BFHI(v0.z);
        a[6] += BFLO(v0.w); a[7] += BFHI(v0.w);
      }
      int node = node0 + dl;
      float invc = 1.0f / fmaxf((float)d, 1.0f);
      uint4 rv = *(const uint4*)&yr[(size_t)node * 64 + f8 * 8];
      float4 bv0 = *(const float4*)&b1[f8 * 8];
      float4 bv1 = *(const float4*)&b1[f8 * 8 + 4];
      float hv[8];
      hv[0] = a[0] * invc + bv0.x + BFLO(rv.x);
      hv[1] = a[1] * invc + bv0.y + BFHI(rv.x);
      hv[2] = a[2] * invc + bv0.z + BFLO(rv.y);
      hv[3] = a[3] * invc + bv0.w + BFHI(rv.y);
      hv[4] = a[4] * invc + bv1.x + BFLO(rv.z);
      hv[5] = a[5] * invc + bv1.y + BFHI(rv.z);
      hv[6] = a[6] * invc + bv1.z + BFLO(rv.w);
      hv[7] = a[7] * invc + bv1.w + BFHI(rv.w);
      *(float4*)&h[(size_t)node * 64 + f8 * 8]     = make_float4(hv[0], hv[1], hv[2], hv[3]);
      *(float4*)&h[(size_t)node * 64 + f8 * 8 + 4] = make_float4(hv[4], hv[5], hv[6], hv[7]);
#pragma unroll
      for (int j = 0; j < 8; ++j) { s[j] += hv[j]; q[j] += hv[j] * hv[j]; }
    }
  }

  // phase 5: BN partials — shfl reduce over groups (stride 8,16,32), LDS stage,
  // then 128 global atomics per block.
#pragma unroll
  for (int j = 0; j < 8; ++j) {
    s[j] += __shfl_xor(s[j], 8);  s[j] += __shfl_xor(s[j], 16); s[j] += __shfl_xor(s[j], 32);
    q[j] += __shfl_xor(q[j], 8);  q[j] += __shfl_xor(q[j], 16); q[j] += __shfl_xor(q[j], 32);
  }
  const int w = tid >> 6, lane = tid & 63;
  if (lane < 8) {
#pragma unroll
    for (int j = 0; j < 8; ++j) {
      bnWs[w][lane * 8 + j] = s[j];
      bnWq[w][lane * 8 + j] = q[j];
    }
  }
  __syncthreads();
  if (tid < 64) {
    float S = 0.f, Q = 0.f;
#pragma unroll
    for (int ww = 0; ww < 8; ++ww) { S += bnWs[ww][tid]; Q += bnWq[ww][tid]; }
    atomicAdd(&bnacc[tid], S);
    atomicAdd(&bnacc[64 + tid], Q);
  }
}

// ---------------------------------------------------------------------------
// k_layer2m (MFMA, BN-finalize fused): h' = relu(bn(h));
// zl = h'@W2_l^T (bf16); zr = h'@W2_r^T + b2 (f32)
// ---------------------------------------------------------------------------
__global__ __launch_bounds__(256) void k_layer2m(const float* __restrict__ h,
                                                 const float* __restrict__ W2l,
                                                 const float* __restrict__ W2r,
                                                 const float* __restrict__ b2,
                                                 const float* __restrict__ bnacc,
                                                 const float* __restrict__ gamma,
                                                 const float* __restrict__ beta,
                                                 ushort* __restrict__ zl,
                                                 float* __restrict__ zr) {
  __shared__ ushort hs[64 * 72];
  __shared__ ushort wss[32 * 72];
  __shared__ float sc[64], sh[64];
  const int tid = threadIdx.x;
  const int n0 = blockIdx.x * 64;

  if (tid < 64) {
    float mean = bnacc[tid] * (1.0f / NN);
    float var = bnacc[64 + tid] * (1.0f / NN) - mean * mean;
    float scv = gamma[tid] * rsqrtf(var + 1e-5f);
    sc[tid] = scv;
    sh[tid] = beta[tid] - mean * scv;
  }
  for (int i = tid; i < 32 * 16; i += 256) {
    int r = i >> 4, c = i & 15;
    const float* src = (r < 16) ? &W2l[r * 64 + c * 4] : &W2r[(r - 16) * 64 + c * 4];
    float4 v = *(const float4*)src;
    *(ushort4*)&wss[r * 72 + c * 4] = make_ushort4(f2bf(v.x), f2bf(v.y), f2bf(v.z), f2bf(v.w));
  }
  __syncthreads();

  for (int i = tid; i < 64 * 16; i += 256) {
    int r = i >> 4, c = i & 15;
    int n = n0 + r;
    float4 v = (n < NN) ? *(const float4*)&h[(size_t)n * 64 + c * 4]
                        : make_float4(0.f, 0.f, 0.f, 0.f);
    float4 o;
    o.x = fmaxf(v.x * sc[c * 4 + 0] + sh[c * 4 + 0], 0.f);
    o.y = fmaxf(v.y * sc[c * 4 + 1] + sh[c * 4 + 1], 0.f);
    o.z = fmaxf(v.z * sc[c * 4 + 2] + sh[c * 4 + 2], 0.f);
    o.w = fmaxf(v.w * sc[c * 4 + 3] + sh[c * 4 + 3], 0.f);
    *(ushort4*)&hs[r * 72 + c * 4] = make_ushort4(f2bf(o.x), f2bf(o.y), f2bf(o.z), f2bf(o.w));
  }
  __syncthreads();

  const int w = tid >> 6, l = tid & 63;
  const int col = l & 15, kb = l >> 4;

  f32x4 acc[2] = {(f32x4){0.f, 0.f, 0.f, 0.f}, (f32x4){0.f, 0.f, 0.f, 0.f}};
#pragma unroll
  for (int kc = 0; kc < 2; ++kc) {
    int koff = kc * 32 + kb * 8;
    bf16x8 a = *(const bf16x8*)&hs[(w * 16 + col) * 72 + koff];
    bf16x8 b0 = *(const bf16x8*)&wss[col * 72 + koff];
    bf16x8 b1v = *(const bf16x8*)&wss[(16 + col) * 72 + koff];
    acc[0] = __builtin_amdgcn_mfma_f32_16x16x32_bf16(a, b0, acc[0], 0, 0, 0);
    acc[1] = __builtin_amdgcn_mfma_f32_16x16x32_bf16(a, b1v, acc[1], 0, 0, 0);
  }

#pragma unroll
  for (int r = 0; r < 4; ++r) {
    int n = n0 + w * 16 + kb * 4 + r;
    if (n < NN) {
      zl[(size_t)n * 16 + col] = f2bf(acc[0][r]);
      zr[(size_t)n * 16 + col] = acc[1][r] + b2[col];
    }
  }
}

// ---------------------------------------------------------------------------
// k_agg2c: per bucket — edges already dst-sorted in ebuf (src list).
// 8-lane group per node, register accumulation; out = sums/deg + zr.
// ---------------------------------------------------------------------------
__global__ __launch_bounds__(512) void k_agg2c(const int* __restrict__ ebuf,
                                               const int* __restrict__ bstart,
                                               const int* __restrict__ bcur,
                                               const int* __restrict__ hist,
                                               const ushort* __restrict__ zl,
                                               const float* __restrict__ zr,
                                               float* __restrict__ out) {
  __shared__ int elist[CAP];
  __shared__ int sd[128], deg[128], offx[128];
  const int tid = threadIdx.x;
  const int b = blockIdx.x;
  const int node0 = b << 7;
  const int nnode = min(NPB, NN - node0);
  const int kstart = bstart[b];
  const int T = bcur[b] - kstart;

  for (int i = tid; i < T; i += 512) elist[i] = ebuf[kstart + i];
  if (tid < 128) {
    int d = (tid < nnode) ? hist[node0 + tid] : 0;
    deg[tid] = d;
    sd[tid] = d;
  }
  __syncthreads();
  for (int o = 1; o < 128; o <<= 1) {
    int v = (tid < 128 && tid >= o) ? sd[tid - o] : 0;
    __syncthreads();
    if (tid < 128) sd[tid] += v;
    __syncthreads();
  }
  if (tid < 128) offx[tid] = sd[tid] - deg[tid];
  __syncthreads();

  const int g = tid >> 3, f8 = tid & 7;
#pragma unroll
  for (int rep = 0; rep < 2; ++rep) {
    int dl = g + rep * 64;
    if (dl < nnode) {
      int st = offx[dl], d = deg[dl];
      float a0 = 0.f, a1 = 0.f;
      int k = st, ke = st + d;
      for (; k + 1 < ke; k += 2) {
        int s0 = elist[k], s1 = elist[k + 1];
        unsigned v0 = *(const unsigned*)&zl[(size_t)s0 * 16 + f8 * 2];
        unsigned v1 = *(const unsigned*)&zl[(size_t)s1 * 16 + f8 * 2];
        a0 += BFLO(v0) + BFLO(v1);
        a1 += BFHI(v0) + BFHI(v1);
      }
      if (k < ke) {
        unsigned v0 = *(const unsigned*)&zl[(size_t)elist[k] * 16 + f8 * 2];
        a0 += BFLO(v0);
        a1 += BFHI(v0);
      }
      int node = node0 + dl;
      float invc = 1.0f / fmaxf((float)d, 1.0f);
      size_t base = (size_t)node * 16 + f8 * 2;
      out[base]     = a0 * invc + zr[base];
      out[base + 1] = a1 * invc + zr[base + 1];
    }
  }
}

// ---------------------------------------------------------------------------
extern "C" void kernel_launch(void* const* d_in, const int* in_sizes, int n_in,
                              void* d_out, int out_size, void* d_ws, size_t ws_size,
                              hipStream_t stream) {
  const float* x     = (const float*)d_in[0];
  const int*   ei    = (const int*)d_in[1];
  const float* W1l   = (const float*)d_in[2];
  const float* b1    = (const float*)d_in[3];
  const float* W1r   = (const float*)d_in[4];
  const float* gamma = (const float*)d_in[5];
  const float* beta  = (const float*)d_in[6];
  const float* W2l   = (const float*)d_in[7];
  const float* b2    = (const float*)d_in[8];
  const float* W2r   = (const float*)d_in[9];
  float* out = (float*)d_out;
  float* ws  = (float*)d_ws;

  float*  hbuf   = ws + OFF_H;
  ushort* yl     = (ushort*)(ws + OFF_YL);
  ushort* yr     = (ushort*)(ws + OFF_YR);
  ushort* zl     = (ushort*)(ws + OFF_YL);   // overlays yl (dead after agg1c)
  float*  zr     = ws + OFF_YR;              // overlays yr (dead after agg1c)
  int*    ebuf   = (int*)(ws + OFF_EBUF);
  int*    hist   = (int*)(ws + OFF_HIST);
  int*    bstart = (int*)(ws + OFF_BSTART);
  int*    bcur   = (int*)(ws + OFF_BCUR);
  float*  bnacc  = ws + OFF_BNACC;

  hipMemsetAsync(hist, 0, NN * sizeof(int), stream);
  hipMemsetAsync(bnacc, 0, 128 * sizeof(float), stream);

  const int ntiles = (NN + 63) / 64;         // 1563
  k_hist<<<(NE + 255) / 256, 256, 0, stream>>>(ei, hist);
  k_bprep<<<1, 1024, 0, stream>>>(hist, bstart, bcur);
  k_part<<<(NE + EPB - 1) / EPB, 256, 0, stream>>>(ei, bcur, ebuf);
  k_gemm12<<<ntiles, 256, 0, stream>>>(x, W1l, W1r, yl, yr);
  k_agg1c<<<NBK, 512, 0, stream>>>(ebuf, bstart, bcur, hist, yl, yr, b1, hbuf, bnacc);
  k_layer2m<<<ntiles, 256, 0, stream>>>(hbuf, W2l, W2r, b2, bnacc, gamma, beta, zl, zr);
  k_agg2c<<<NBK, 512, 0, stream>>>(ebuf, bstart, bcur, hist, zl, zr, out);
}

// Round 13
// 175.720 us; speedup vs baseline: 5.9468x; 1.4541x over previous
//
#include <hip/hip_runtime.h>

#define NN 100000
#define NE 1600000
#define NPB 128                 // nodes per bucket
#define NBK 782                 // ceil(NN/128)
#define EPB 16384               // edges per partition block
#define CAP 4096                // max edges per bucket in LDS (mean 2048, sigma 45)

// workspace word offsets (ends 14,502,474 words = 58.01 MB)
#define OFF_H      0            // h f32 [N,64] (6.4M words)
#define OFF_YL     6400000      // yl bf16 [N,64]; zl bf16 [N,16] overlays after agg1c
#define OFF_YR     9600000      // yr bf16 [N,64]; zr f32 [N,16] overlays after agg1c
#define OFF_EBUF   12800000     // packed edges int x 1.6M (raw -> sorted src in place)
#define OFF_HIST   14400000     // 100,000 i  (degrees; WRITTEN by agg1c, read by agg2c)
#define OFF_BSTART 14500000     // 782 i
#define OFF_BCUR   14500782     // 782 i
#define OFF_BCNT   14501564     // 782 i   (zeroed each call, with bnacc)
#define OFF_BNACC  14502346     // 128 f

typedef __attribute__((ext_vector_type(8))) short bf16x8;
typedef __attribute__((ext_vector_type(4))) float f32x4;

__device__ __forceinline__ ushort f2bf(float f) {   // RNE f32 -> bf16
  unsigned u = __float_as_uint(f);
  u += 0x7fffu + ((u >> 16) & 1);
  return (ushort)(u >> 16);
}
#define BFLO(u) __uint_as_float(((u) & 0xffffu) << 16)
#define BFHI(u) __uint_as_float((u) & 0xffff0000u)

// ---------------------------------------------------------------------------
// k_bcnt2: per-bucket edge counts (LDS histogram of 782 buckets, then one
// global int atomic per bucket per block — 76K atomics total, not 1.6M)
// ---------------------------------------------------------------------------
__global__ __launch_bounds__(1024) void k_bcnt2(const int* __restrict__ ei,
                                                int* __restrict__ bcnt) {
  __shared__ int cnt[NBK];
  const int tid = threadIdx.x;
  for (int i = tid; i < NBK; i += 1024) cnt[i] = 0;
  __syncthreads();
  const int per = (NE + gridDim.x - 1) / gridDim.x;
  int e0 = blockIdx.x * per;
  int e1 = min(e0 + per, NE);
  for (int e = e0 + tid; e < e1; e += 1024)
    atomicAdd(&cnt[ei[NE + e] >> 7], 1);
  __syncthreads();
  for (int b = tid; b < NBK; b += 1024)
    if (cnt[b]) atomicAdd(&bcnt[b], cnt[b]);
}

// ---------------------------------------------------------------------------
// k_bprep: exclusive scan of bcnt -> bstart, bcur (one block)
// ---------------------------------------------------------------------------
__global__ __launch_bounds__(1024) void k_bprep(const int* __restrict__ bcnt,
                                                int* __restrict__ bstart,
                                                int* __restrict__ bcur) {
  __shared__ int sd[1024];
  int t = threadIdx.x;
  int v = (t < NBK) ? bcnt[t] : 0;
  sd[t] = v;
  __syncthreads();
  for (int off = 1; off < 1024; off <<= 1) {
    int u = (t >= off) ? sd[t - off] : 0;
    __syncthreads();
    sd[t] += u;
    __syncthreads();
  }
  if (t < NBK) { int s = sd[t] - v; bstart[t] = s; bcur[t] = s; }
}

// ---------------------------------------------------------------------------
// partition edges into bucket-contiguous regions, packed (src<<7 | dst&127)
// ---------------------------------------------------------------------------
__global__ __launch_bounds__(256) void k_part(const int* __restrict__ ei,
                                              int* __restrict__ bcur,
                                              int* __restrict__ ebuf) {
  __shared__ int cnt[NBK], gstart[NBK], cur[NBK];
  int e0 = blockIdx.x * EPB;
  int e1 = min(e0 + EPB, NE);
  for (int i = threadIdx.x; i < NBK; i += 256) cnt[i] = 0;
  __syncthreads();
  for (int e = e0 + threadIdx.x; e < e1; e += 256)
    atomicAdd(&cnt[ei[NE + e] >> 7], 1);
  __syncthreads();
  for (int b = threadIdx.x; b < NBK; b += 256) {
    int c = cnt[b];
    gstart[b] = c ? atomicAdd(&bcur[b], c) : 0;
    cur[b] = 0;
  }
  __syncthreads();
  for (int e = e0 + threadIdx.x; e < e1; e += 256) {
    int s = ei[e], t = ei[NE + e];
    int b = t >> 7;
    int r = atomicAdd(&cur[b], 1);
    ebuf[gstart[b] + r] = (s << 7) | (t & 127);
  }
}

// ---------------------------------------------------------------------------
// k_gemm12 (MFMA): yl = x@W1l^T, yr = x@W1r^T (both bf16), x staged once.
// ---------------------------------------------------------------------------
__global__ __launch_bounds__(256) void k_gemm12(const float* __restrict__ x,
                                                const float* __restrict__ W1l,
                                                const float* __restrict__ W1r,
                                                ushort* __restrict__ yl,
                                                ushort* __restrict__ yr) {
  __shared__ ushort xs[64 * 136];
  __shared__ ushort wss[128 * 136];
  const int tid = threadIdx.x;
  const int n0 = blockIdx.x * 64;

  for (int i = tid; i < 64 * 32; i += 256) {
    int r = i >> 5, c = i & 31;
    int n = n0 + r;
    float4 v = (n < NN) ? *(const float4*)&x[(size_t)n * 128 + c * 4]
                        : make_float4(0.f, 0.f, 0.f, 0.f);
    *(ushort4*)&xs[r * 136 + c * 4] = make_ushort4(f2bf(v.x), f2bf(v.y), f2bf(v.z), f2bf(v.w));
  }
  for (int i = tid; i < 128 * 32; i += 256) {
    int r = i >> 5, c = i & 31;
    const float* src = (r < 64) ? &W1l[r * 128 + c * 4] : &W1r[(r - 64) * 128 + c * 4];
    float4 v = *(const float4*)src;
    *(ushort4*)&wss[r * 136 + c * 4] = make_ushort4(f2bf(v.x), f2bf(v.y), f2bf(v.z), f2bf(v.w));
  }
  __syncthreads();

  const int w = tid >> 6, l = tid & 63;
  const int col = l & 15, kb = l >> 4;

  f32x4 acc[4][2];
#pragma unroll
  for (int nt = 0; nt < 4; ++nt)
#pragma unroll
    for (int ot = 0; ot < 2; ++ot) acc[nt][ot] = (f32x4){0.f, 0.f, 0.f, 0.f};

#pragma unroll
  for (int kc = 0; kc < 4; ++kc) {
    int koff = kc * 32 + kb * 8;
    bf16x8 a[4], b[2];
#pragma unroll
    for (int nt = 0; nt < 4; ++nt)
      a[nt] = *(const bf16x8*)&xs[(nt * 16 + col) * 136 + koff];
#pragma unroll
    for (int ot = 0; ot < 2; ++ot)
      b[ot] = *(const bf16x8*)&wss[((w * 2 + ot) * 16 + col) * 136 + koff];
#pragma unroll
    for (int nt = 0; nt < 4; ++nt)
#pragma unroll
      for (int ot = 0; ot < 2; ++ot)
        acc[nt][ot] = __builtin_amdgcn_mfma_f32_16x16x32_bf16(a[nt], b[ot], acc[nt][ot], 0, 0, 0);
  }

#pragma unroll
  for (int nt = 0; nt < 4; ++nt)
#pragma unroll
    for (int ot = 0; ot < 2; ++ot) {
      int outc = (w * 2 + ot) * 16 + col;
#pragma unroll
      for (int r = 0; r < 4; ++r) {
        int n = n0 + nt * 16 + kb * 4 + r;
        if (n < NN) {
          ushort v = f2bf(acc[nt][ot][r]);
          if (outc < 64) yl[(size_t)n * 64 + outc] = v;
          else           yr[(size_t)n * 64 + (outc - 64)] = v;
        }
      }
    }
}

// ---------------------------------------------------------------------------
// k_agg1c: per bucket — derive degrees in LDS (int atomics), counting-sort
// edges by dst, 8-lane groups accumulate each node's contiguous edge list in
// registers. Writes sorted src list back to ebuf and degrees to hist.
// h = sums/deg + b1 + yr; BN partials via shfl reduce (no float atomics).
// ---------------------------------------------------------------------------
__global__ __launch_bounds__(512) void k_agg1c(int* __restrict__ ebuf,
                                               const int* __restrict__ bstart,
                                               const int* __restrict__ bcnt,
                                               int* __restrict__ hist,
                                               const ushort* __restrict__ yl,
                                               const ushort* __restrict__ yr,
                                               const float* __restrict__ b1,
                                               float* __restrict__ h,
                                               float* __restrict__ bnacc) {
  __shared__ int raw[CAP];
  __shared__ int srt[CAP];
  __shared__ int sd[128], deg[128], offx[128], cursor[128];
  __shared__ float bnWs[8][64], bnWq[8][64];
  const int tid = threadIdx.x;
  const int b = blockIdx.x;
  const int node0 = b << 7;
  const int nnode = min(NPB, NN - node0);
  const int kstart = bstart[b];
  const int T = min(bcnt[b], CAP);

  // phase 1: stage raw edges + LDS degree count
  if (tid < 128) deg[tid] = 0;
  __syncthreads();
  for (int i = tid; i < T; i += 512) {
    int e = ebuf[kstart + i];
    raw[i] = e;
    atomicAdd(&deg[e & 127], 1);
  }
  __syncthreads();
  if (tid < 128) sd[tid] = deg[tid];
  __syncthreads();
  for (int o = 1; o < 128; o <<= 1) {
    int v = (tid < 128 && tid >= o) ? sd[tid - o] : 0;
    __syncthreads();
    if (tid < 128) sd[tid] += v;
    __syncthreads();
  }
  if (tid < 128) {
    int s = sd[tid] - deg[tid];
    offx[tid] = s;
    cursor[tid] = s;
    if (tid < nnode) hist[node0 + tid] = deg[tid];   // coalesced degree write
  }
  __syncthreads();

  // phase 2: counting sort by dst (native int LDS atomics)
  for (int i = tid; i < T; i += 512) {
    int e = raw[i];
    int slot = atomicAdd(&cursor[e & 127], 1);
    srt[slot] = e >> 7;
  }
  __syncthreads();

  // phase 3: write sorted src list back to global (for agg2c)
  for (int i = tid; i < T; i += 512) ebuf[kstart + i] = srt[i];

  // phase 4: register accumulation, 8-lane group per node
  const int g = tid >> 3, f8 = tid & 7;
  float s[8] = {}, q[8] = {};
#pragma unroll
  for (int rep = 0; rep < 2; ++rep) {
    int dl = g + rep * 64;
    if (dl < nnode) {
      int st = offx[dl], d = deg[dl];
      float a[8] = {};
      int k = st, ke = st + d;
      for (; k + 1 < ke; k += 2) {
        int s0 = srt[k], s1 = srt[k + 1];
        uint4 v0 = *(const uint4*)&yl[(size_t)s0 * 64 + f8 * 8];
        uint4 v1 = *(const uint4*)&yl[(size_t)s1 * 64 + f8 * 8];
        a[0] += BFLO(v0.x) + BFLO(v1.x); a[1] += BFHI(v0.x) + BFHI(v1.x);
        a[2] += BFLO(v0.y) + BFLO(v1.y); a[3] += BFHI(v0.y) + BFHI(v1.y);
        a[4] += BFLO(v0.z) + BFLO(v1.z); a[5] += BFHI(v0.z) + BFHI(v1.z);
        a[6] += BFLO(v0.w) + BFLO(v1.w); a[7] += BFHI(v0.w) + BFHI(v1.w);
      }
      if (k < ke) {
        int s0 = srt[k];
        uint4 v0 = *(const uint4*)&yl[(size_t)s0 * 64 + f8 * 8];
        a[0] += BFLO(v0.x); a[1] += BFHI(v0.x);
        a[2] += BFLO(v0.y); a[3] += BFHI(v0.y);
        a[4] += BFLO(v0.z); a[5] += BFHI(v0.z);
        a[6] += BFLO(v0.w); a[7] += BFHI(v0.w);
      }
      int node = node0 + dl;
      float invc = 1.0f / fmaxf((float)d, 1.0f);
      uint4 rv = *(const uint4*)&yr[(size_t)node * 64 + f8 * 8];
      float4 bv0 = *(const float4*)&b1[f8 * 8];
      float4 bv1 = *(const float4*)&b1[f8 * 8 + 4];
      float hv[8];
      hv[0] = a[0] * invc + bv0.x + BFLO(rv.x);
      hv[1] = a[1] * invc + bv0.y + BFHI(rv.x);
      hv[2] = a[2] * invc + bv0.z + BFLO(rv.y);
      hv[3] = a[3] * invc + bv0.w + BFHI(rv.y);
      hv[4] = a[4] * invc + bv1.x + BFLO(rv.z);
      hv[5] = a[5] * invc + bv1.y + BFHI(rv.z);
      hv[6] = a[6] * invc + bv1.z + BFLO(rv.w);
      hv[7] = a[7] * invc + bv1.w + BFHI(rv.w);
      *(float4*)&h[(size_t)node * 64 + f8 * 8]     = make_float4(hv[0], hv[1], hv[2], hv[3]);
      *(float4*)&h[(size_t)node * 64 + f8 * 8 + 4] = make_float4(hv[4], hv[5], hv[6], hv[7]);
#pragma unroll
      for (int j = 0; j < 8; ++j) { s[j] += hv[j]; q[j] += hv[j] * hv[j]; }
    }
  }

  // phase 5: BN partials — shfl reduce, LDS stage, 128 global atomics/block
#pragma unroll
  for (int j = 0; j < 8; ++j) {
    s[j] += __shfl_xor(s[j], 8);  s[j] += __shfl_xor(s[j], 16); s[j] += __shfl_xor(s[j], 32);
    q[j] += __shfl_xor(q[j], 8);  q[j] += __shfl_xor(q[j], 16); q[j] += __shfl_xor(q[j], 32);
  }
  const int w = tid >> 6, lane = tid & 63;
  if (lane < 8) {
#pragma unroll
    for (int j = 0; j < 8; ++j) {
      bnWs[w][lane * 8 + j] = s[j];
      bnWq[w][lane * 8 + j] = q[j];
    }
  }
  __syncthreads();
  if (tid < 64) {
    float S = 0.f, Q = 0.f;
#pragma unroll
    for (int ww = 0; ww < 8; ++ww) { S += bnWs[ww][tid]; Q += bnWq[ww][tid]; }
    atomicAdd(&bnacc[tid], S);
    atomicAdd(&bnacc[64 + tid], Q);
  }
}

// ---------------------------------------------------------------------------
// k_layer2m (MFMA, BN-finalize fused): h' = relu(bn(h));
// zl = h'@W2_l^T (bf16); zr = h'@W2_r^T + b2 (f32)
// ---------------------------------------------------------------------------
__global__ __launch_bounds__(256) void k_layer2m(const float* __restrict__ h,
                                                 const float* __restrict__ W2l,
                                                 const float* __restrict__ W2r,
                                                 const float* __restrict__ b2,
                                                 const float* __restrict__ bnacc,
                                                 const float* __restrict__ gamma,
                                                 const float* __restrict__ beta,
                                                 ushort* __restrict__ zl,
                                                 float* __restrict__ zr) {
  __shared__ ushort hs[64 * 72];
  __shared__ ushort wss[32 * 72];
  __shared__ float sc[64], sh[64];
  const int tid = threadIdx.x;
  const int n0 = blockIdx.x * 64;

  if (tid < 64) {
    float mean = bnacc[tid] * (1.0f / NN);
    float var = bnacc[64 + tid] * (1.0f / NN) - mean * mean;
    float scv = gamma[tid] * rsqrtf(var + 1e-5f);
    sc[tid] = scv;
    sh[tid] = beta[tid] - mean * scv;
  }
  for (int i = tid; i < 32 * 16; i += 256) {
    int r = i >> 4, c = i & 15;
    const float* src = (r < 16) ? &W2l[r * 64 + c * 4] : &W2r[(r - 16) * 64 + c * 4];
    float4 v = *(const float4*)src;
    *(ushort4*)&wss[r * 72 + c * 4] = make_ushort4(f2bf(v.x), f2bf(v.y), f2bf(v.z), f2bf(v.w));
  }
  __syncthreads();

  for (int i = tid; i < 64 * 16; i += 256) {
    int r = i >> 4, c = i & 15;
    int n = n0 + r;
    float4 v = (n < NN) ? *(const float4*)&h[(size_t)n * 64 + c * 4]
                        : make_float4(0.f, 0.f, 0.f, 0.f);
    float4 o;
    o.x = fmaxf(v.x * sc[c * 4 + 0] + sh[c * 4 + 0], 0.f);
    o.y = fmaxf(v.y * sc[c * 4 + 1] + sh[c * 4 + 1], 0.f);
    o.z = fmaxf(v.z * sc[c * 4 + 2] + sh[c * 4 + 2], 0.f);
    o.w = fmaxf(v.w * sc[c * 4 + 3] + sh[c * 4 + 3], 0.f);
    *(ushort4*)&hs[r * 72 + c * 4] = make_ushort4(f2bf(o.x), f2bf(o.y), f2bf(o.z), f2bf(o.w));
  }
  __syncthreads();

  const int w = tid >> 6, l = tid & 63;
  const int col = l & 15, kb = l >> 4;

  f32x4 acc[2] = {(f32x4){0.f, 0.f, 0.f, 0.f}, (f32x4){0.f, 0.f, 0.f, 0.f}};
#pragma unroll
  for (int kc = 0; kc < 2; ++kc) {
    int koff = kc * 32 + kb * 8;
    bf16x8 a = *(const bf16x8*)&hs[(w * 16 + col) * 72 + koff];
    bf16x8 b0 = *(const bf16x8*)&wss[col * 72 + koff];
    bf16x8 b1v = *(const bf16x8*)&wss[(16 + col) * 72 + koff];
    acc[0] = __builtin_amdgcn_mfma_f32_16x16x32_bf16(a, b0, acc[0], 0, 0, 0);
    acc[1] = __builtin_amdgcn_mfma_f32_16x16x32_bf16(a, b1v, acc[1], 0, 0, 0);
  }

#pragma unroll
  for (int r = 0; r < 4; ++r) {
    int n = n0 + w * 16 + kb * 4 + r;
    if (n < NN) {
      zl[(size_t)n * 16 + col] = f2bf(acc[0][r]);
      zr[(size_t)n * 16 + col] = acc[1][r] + b2[col];
    }
  }
}

// ---------------------------------------------------------------------------
// k_agg2c: per bucket — edges already dst-sorted in ebuf (src list).
// 8-lane group per node, register accumulation; out = sums/deg + zr.
// ---------------------------------------------------------------------------
__global__ __launch_bounds__(512) void k_agg2c(const int* __restrict__ ebuf,
                                               const int* __restrict__ bstart,
                                               const int* __restrict__ bcnt,
                                               const int* __restrict__ hist,
                                               const ushort* __restrict__ zl,
                                               const float* __restrict__ zr,
                                               float* __restrict__ out) {
  __shared__ int elist[CAP];
  __shared__ int sd[128], deg[128], offx[128];
  const int tid = threadIdx.x;
  const int b = blockIdx.x;
  const int node0 = b << 7;
  const int nnode = min(NPB, NN - node0);
  const int kstart = bstart[b];
  const int T = min(bcnt[b], CAP);

  for (int i = tid; i < T; i += 512) elist[i] = ebuf[kstart + i];
  if (tid < 128) {
    int d = (tid < nnode) ? hist[node0 + tid] : 0;
    deg[tid] = d;
    sd[tid] = d;
  }
  __syncthreads();
  for (int o = 1; o < 128; o <<= 1) {
    int v = (tid < 128 && tid >= o) ? sd[tid - o] : 0;
    __syncthreads();
    if (tid < 128) sd[tid] += v;
    __syncthreads();
  }
  if (tid < 128) offx[tid] = sd[tid] - deg[tid];
  __syncthreads();

  const int g = tid >> 3, f8 = tid & 7;
#pragma unroll
  for (int rep = 0; rep < 2; ++rep) {
    int dl = g + rep * 64;
    if (dl < nnode) {
      int st = offx[dl], d = deg[dl];
      float a0 = 0.f, a1 = 0.f;
      int k = st, ke = st + d;
      for (; k + 1 < ke; k += 2) {
        int s0 = elist[k], s1 = elist[k + 1];
        unsigned v0 = *(const unsigned*)&zl[(size_t)s0 * 16 + f8 * 2];
        unsigned v1 = *(const unsigned*)&zl[(size_t)s1 * 16 + f8 * 2];
        a0 += BFLO(v0) + BFLO(v1);
        a1 += BFHI(v0) + BFHI(v1);
      }
      if (k < ke) {
        unsigned v0 = *(const unsigned*)&zl[(size_t)elist[k] * 16 + f8 * 2];
        a0 += BFLO(v0);
        a1 += BFHI(v0);
      }
      int node = node0 + dl;
      float invc = 1.0f / fmaxf((float)d, 1.0f);
      size_t base = (size_t)node * 16 + f8 * 2;
      out[base]     = a0 * invc + zr[base];
      out[base + 1] = a1 * invc + zr[base + 1];
    }
  }
}

// ---------------------------------------------------------------------------
extern "C" void kernel_launch(void* const* d_in, const int* in_sizes, int n_in,
                              void* d_out, int out_size, void* d_ws, size_t ws_size,
                              hipStream_t stream) {
  const float* x     = (const float*)d_in[0];
  const int*   ei    = (const int*)d_in[1];
  const float* W1l   = (const float*)d_in[2];
  const float* b1    = (const float*)d_in[3];
  const float* W1r   = (const float*)d_in[4];
  const float* gamma = (const float*)d_in[5];
  const float* beta  = (const float*)d_in[6];
  const float* W2l   = (const float*)d_in[7];
  const float* b2    = (const float*)d_in[8];
  const float* W2r   = (const float*)d_in[9];
  float* out = (float*)d_out;
  float* ws  = (float*)d_ws;

  float*  hbuf   = ws + OFF_H;
  ushort* yl     = (ushort*)(ws + OFF_YL);
  ushort* yr     = (ushort*)(ws + OFF_YR);
  ushort* zl     = (ushort*)(ws + OFF_YL);   // overlays yl (dead after agg1c)
  float*  zr     = ws + OFF_YR;              // overlays yr (dead after agg1c)
  int*    ebuf   = (int*)(ws + OFF_EBUF);
  int*    hist   = (int*)(ws + OFF_HIST);    // written by agg1c
  int*    bstart = (int*)(ws + OFF_BSTART);
  int*    bcur   = (int*)(ws + OFF_BCUR);
  int*    bcnt   = (int*)(ws + OFF_BCNT);
  float*  bnacc  = ws + OFF_BNACC;

  // bcnt (782 i) and bnacc (128 f) are adjacent -> one small memset
  hipMemsetAsync(bcnt, 0, (782 + 128) * sizeof(int), stream);

  const int ntiles = (NN + 63) / 64;         // 1563
  k_bcnt2<<<98, 1024, 0, stream>>>(ei, bcnt);
  k_bprep<<<1, 1024, 0, stream>>>(bcnt, bstart, bcur);
  k_part<<<(NE + EPB - 1) / EPB, 256, 0, stream>>>(ei, bcur, ebuf);
  k_gemm12<<<ntiles, 256, 0, stream>>>(x, W1l, W1r, yl, yr);
  k_agg1c<<<NBK, 512, 0, stream>>>(ebuf, bstart, bcnt, hist, yl, yr, b1, hbuf, bnacc);
  k_layer2m<<<ntiles, 256, 0, stream>>>(hbuf, W2l, W2r, b2, bnacc, gamma, beta, zl, zr);
  k_agg2c<<<NBK, 512, 0, stream>>>(ebuf, bstart, bcnt, hist, zl, zr, out);
}

// Round 14
// 146.656 us; speedup vs baseline: 7.1253x; 1.1982x over previous
//
#include <hip/hip_runtime.h>

#define NN 100000
#define NE 1600000
#define NPB 128                 // nodes per bucket
#define NBK 782                 // ceil(NN/128)
#define EPB 4096                // edges per partition block
#define NPART 391               // ceil(NE/EPB)
#define NTILES 1563             // ceil(NN/64) gemm tiles
#define CAP 4096                // max edges per bucket in LDS

// workspace word offsets (ends 14,525,952 words = 58.1 MB)
#define OFF_H      0            // h f32 [N,64]
#define OFF_YL     6400000      // yl bf16 [N,64]; zl bf16 [N,16] overlays after agg1c
#define OFF_YR     9600000      // yr bf16 [N,64]; zr f32 [N,16] overlays after agg1c
#define OFF_EBUF   12800000     // packed edges int x 1.6M (raw -> sorted src in place)
#define OFF_HIST   14400000     // 100,000 i (degrees; written by agg1c, read by agg2c)
#define OFF_BSTART 14500000     // 783 i (incl sentinel)
#define OFF_BCURP  14500800     // 782*16 i (line-padded cursors)
#define OFF_BCNTP  14513312     // 782*16 i (line-padded counts; zeroed)
#define OFF_BNACC  14525824     // 128 f (zeroed)

typedef __attribute__((ext_vector_type(8))) short bf16x8;
typedef __attribute__((ext_vector_type(4))) float f32x4;

__device__ __forceinline__ ushort f2bf(float f) {   // RNE f32 -> bf16
  unsigned u = __float_as_uint(f);
  u += 0x7fffu + ((u >> 16) & 1);
  return (ushort)(u >> 16);
}
#define BFLO(u) __uint_as_float(((u) & 0xffffu) << 16)
#define BFHI(u) __uint_as_float((u) & 0xffff0000u)

// ---------------------------------------------------------------------------
// k_bcnt2: per-bucket edge counts (LDS histogram, then 1 padded global atomic
// per bucket per block)
// ---------------------------------------------------------------------------
__global__ __launch_bounds__(1024) void k_bcnt2(const int* __restrict__ ei,
                                                int* __restrict__ bcntp) {
  __shared__ int cnt[NBK];
  const int tid = threadIdx.x;
  for (int i = tid; i < NBK; i += 1024) cnt[i] = 0;
  __syncthreads();
  const int per = (NE + gridDim.x - 1) / gridDim.x;
  int e0 = blockIdx.x * per;
  int e1 = min(e0 + per, NE);
  for (int e = e0 + tid; e < e1; e += 1024)
    atomicAdd(&cnt[ei[NE + e] >> 7], 1);
  __syncthreads();
  for (int b = tid; b < NBK; b += 1024)
    if (cnt[b]) atomicAdd(&bcntp[b * 16], cnt[b]);
}

// ---------------------------------------------------------------------------
// k_bprep: exclusive scan of bcntp -> bstart (+sentinel), seed padded bcur
// ---------------------------------------------------------------------------
__global__ __launch_bounds__(1024) void k_bprep(const int* __restrict__ bcntp,
                                                int* __restrict__ bstart,
                                                int* __restrict__ bcurp) {
  __shared__ int sd[1024];
  int t = threadIdx.x;
  int v = (t < NBK) ? bcntp[t * 16] : 0;
  sd[t] = v;
  __syncthreads();
  for (int off = 1; off < 1024; off <<= 1) {
    int u = (t >= off) ? sd[t - off] : 0;
    __syncthreads();
    sd[t] += u;
    __syncthreads();
  }
  if (t < NBK) { int s = sd[t] - v; bstart[t] = s; bcurp[t * 16] = s; }
  if (t == 0) bstart[NBK] = NE;
}

// ---------------------------------------------------------------------------
// k_pg: FUSED partition + gemm12.
//   blocks [0, NPART): partition edges into bucket regions (packed src<<7|dl)
//   blocks [NPART, NPART+NTILES): MFMA gemm yl = x@W1l^T, yr = x@W1r^T
// Both are independent; they join at k_agg1c.
// ---------------------------------------------------------------------------
__global__ __launch_bounds__(512) void k_pg(const int* __restrict__ ei,
                                            int* __restrict__ bcurp,
                                            int* __restrict__ ebuf,
                                            const float* __restrict__ x,
                                            const float* __restrict__ W1l,
                                            const float* __restrict__ W1r,
                                            ushort* __restrict__ yl,
                                            ushort* __restrict__ yr) {
  __shared__ ushort smem[64 * 136 + 128 * 136];   // 52.2 KB
  const int tid = threadIdx.x;

  if (blockIdx.x < NPART) {
    // ---- partition branch ----
    int* cnt = (int*)smem;
    int* gstart = cnt + NBK;
    int* cur = gstart + NBK;
    int e0 = blockIdx.x * EPB;
    int e1 = min(e0 + EPB, NE);
    for (int i = tid; i < NBK; i += 512) cnt[i] = 0;
    __syncthreads();
    for (int e = e0 + tid; e < e1; e += 512)
      atomicAdd(&cnt[ei[NE + e] >> 7], 1);
    __syncthreads();
    for (int b = tid; b < NBK; b += 512) {
      int c = cnt[b];
      gstart[b] = c ? atomicAdd(&bcurp[b * 16], c) : 0;
      cur[b] = 0;
    }
    __syncthreads();
    for (int e = e0 + tid; e < e1; e += 512) {
      int s = ei[e], t = ei[NE + e];
      int b = t >> 7;
      int r = atomicAdd(&cur[b], 1);
      ebuf[gstart[b] + r] = (s << 7) | (t & 127);
    }
    return;
  }

  // ---- gemm branch (8 waves, wave w owns out-tile w) ----
  ushort* xs = smem;               // 64 x 136
  ushort* wss = smem + 64 * 136;   // 128 x 136
  const int n0 = (blockIdx.x - NPART) * 64;

  for (int i = tid; i < 64 * 32; i += 512) {
    int r = i >> 5, c = i & 31;
    int n = n0 + r;
    float4 v = (n < NN) ? *(const float4*)&x[(size_t)n * 128 + c * 4]
                        : make_float4(0.f, 0.f, 0.f, 0.f);
    *(ushort4*)&xs[r * 136 + c * 4] = make_ushort4(f2bf(v.x), f2bf(v.y), f2bf(v.z), f2bf(v.w));
  }
  for (int i = tid; i < 128 * 32; i += 512) {
    int r = i >> 5, c = i & 31;
    const float* src = (r < 64) ? &W1l[r * 128 + c * 4] : &W1r[(r - 64) * 128 + c * 4];
    float4 v = *(const float4*)src;
    *(ushort4*)&wss[r * 136 + c * 4] = make_ushort4(f2bf(v.x), f2bf(v.y), f2bf(v.z), f2bf(v.w));
  }
  __syncthreads();

  const int w = tid >> 6, l = tid & 63;
  const int col = l & 15, kb = l >> 4;

  f32x4 acc[4];
#pragma unroll
  for (int nt = 0; nt < 4; ++nt) acc[nt] = (f32x4){0.f, 0.f, 0.f, 0.f};

#pragma unroll
  for (int kc = 0; kc < 4; ++kc) {
    int koff = kc * 32 + kb * 8;
    bf16x8 a[4];
#pragma unroll
    for (int nt = 0; nt < 4; ++nt)
      a[nt] = *(const bf16x8*)&xs[(nt * 16 + col) * 136 + koff];
    bf16x8 b = *(const bf16x8*)&wss[(w * 16 + col) * 136 + koff];
#pragma unroll
    for (int nt = 0; nt < 4; ++nt)
      acc[nt] = __builtin_amdgcn_mfma_f32_16x16x32_bf16(a[nt], b, acc[nt], 0, 0, 0);
  }

  const int outc = w * 16 + col;
#pragma unroll
  for (int nt = 0; nt < 4; ++nt) {
#pragma unroll
    for (int r = 0; r < 4; ++r) {
      int n = n0 + nt * 16 + kb * 4 + r;
      if (n < NN) {
        ushort v = f2bf(acc[nt][r]);
        if (outc < 64) yl[(size_t)n * 64 + outc] = v;
        else           yr[(size_t)n * 64 + (outc - 64)] = v;
      }
    }
  }
}

// ---------------------------------------------------------------------------
// k_agg1c: per bucket — LDS degree count, counting-sort by dst, 8-lane groups
// accumulate contiguous edge lists in registers (unroll-4 gathers).
// Writes sorted src list back to ebuf and degrees to hist.
// h = sums/deg + b1 + yr; BN partials via shfl reduce.
// ---------------------------------------------------------------------------
__global__ __launch_bounds__(512) void k_agg1c(int* __restrict__ ebuf,
                                               const int* __restrict__ bstart,
                                               int* __restrict__ hist,
                                               const ushort* __restrict__ yl,
                                               const ushort* __restrict__ yr,
                                               const float* __restrict__ b1,
                                               float* __restrict__ h,
                                               float* __restrict__ bnacc) {
  __shared__ int raw[CAP];
  __shared__ int srt[CAP];
  __shared__ int sd[128], deg[128], offx[128], cursor[128];
  __shared__ float bnWs[8][64], bnWq[8][64];
  const int tid = threadIdx.x;
  const int b = blockIdx.x;
  const int node0 = b << 7;
  const int nnode = min(NPB, NN - node0);
  const int kstart = bstart[b];
  const int T = min(bstart[b + 1] - kstart, CAP);

  // phase 1: stage raw edges + LDS degree count
  if (tid < 128) deg[tid] = 0;
  __syncthreads();
  for (int i = tid; i < T; i += 512) {
    int e = ebuf[kstart + i];
    raw[i] = e;
    atomicAdd(&deg[e & 127], 1);
  }
  __syncthreads();
  if (tid < 128) sd[tid] = deg[tid];
  __syncthreads();
  for (int o = 1; o < 128; o <<= 1) {
    int v = (tid < 128 && tid >= o) ? sd[tid - o] : 0;
    __syncthreads();
    if (tid < 128) sd[tid] += v;
    __syncthreads();
  }
  if (tid < 128) {
    int s = sd[tid] - deg[tid];
    offx[tid] = s;
    cursor[tid] = s;
    if (tid < nnode) hist[node0 + tid] = deg[tid];
  }
  __syncthreads();

  // phase 2: counting sort by dst
  for (int i = tid; i < T; i += 512) {
    int e = raw[i];
    int slot = atomicAdd(&cursor[e & 127], 1);
    srt[slot] = e >> 7;
  }
  __syncthreads();

  // phase 3: write sorted src list back (for agg2c)
  for (int i = tid; i < T; i += 512) ebuf[kstart + i] = srt[i];

  // phase 4: register accumulation, 8-lane group per node, unroll-4
  const int g = tid >> 3, f8 = tid & 7;
  float s[8] = {}, q[8] = {};
#pragma unroll
  for (int rep = 0; rep < 2; ++rep) {
    int dl = g + rep * 64;
    if (dl < nnode) {
      int st = offx[dl], d = deg[dl];
      float a[8] = {};
      int k = st, ke = st + d;
      for (; k + 3 < ke; k += 4) {
        int s0 = srt[k], s1 = srt[k + 1], s2 = srt[k + 2], s3 = srt[k + 3];
        uint4 v0 = *(const uint4*)&yl[(size_t)s0 * 64 + f8 * 8];
        uint4 v1 = *(const uint4*)&yl[(size_t)s1 * 64 + f8 * 8];
        uint4 v2 = *(const uint4*)&yl[(size_t)s2 * 64 + f8 * 8];
        uint4 v3 = *(const uint4*)&yl[(size_t)s3 * 64 + f8 * 8];
        a[0] += (BFLO(v0.x) + BFLO(v1.x)) + (BFLO(v2.x) + BFLO(v3.x));
        a[1] += (BFHI(v0.x) + BFHI(v1.x)) + (BFHI(v2.x) + BFHI(v3.x));
        a[2] += (BFLO(v0.y) + BFLO(v1.y)) + (BFLO(v2.y) + BFLO(v3.y));
        a[3] += (BFHI(v0.y) + BFHI(v1.y)) + (BFHI(v2.y) + BFHI(v3.y));
        a[4] += (BFLO(v0.z) + BFLO(v1.z)) + (BFLO(v2.z) + BFLO(v3.z));
        a[5] += (BFHI(v0.z) + BFHI(v1.z)) + (BFHI(v2.z) + BFHI(v3.z));
        a[6] += (BFLO(v0.w) + BFLO(v1.w)) + (BFLO(v2.w) + BFLO(v3.w));
        a[7] += (BFHI(v0.w) + BFHI(v1.w)) + (BFHI(v2.w) + BFHI(v3.w));
      }
      for (; k < ke; ++k) {
        int s0 = srt[k];
        uint4 v0 = *(const uint4*)&yl[(size_t)s0 * 64 + f8 * 8];
        a[0] += BFLO(v0.x); a[1] += BFHI(v0.x);
        a[2] += BFLO(v0.y); a[3] += BFHI(v0.y);
        a[4] += BFLO(v0.z); a[5] += BFHI(v0.z);
        a[6] += BFLO(v0.w); a[7] += BFHI(v0.w);
      }
      int node = node0 + dl;
      float invc = 1.0f / fmaxf((float)d, 1.0f);
      uint4 rv = *(const uint4*)&yr[(size_t)node * 64 + f8 * 8];
      float4 bv0 = *(const float4*)&b1[f8 * 8];
      float4 bv1 = *(const float4*)&b1[f8 * 8 + 4];
      float hv[8];
      hv[0] = a[0] * invc + bv0.x + BFLO(rv.x);
      hv[1] = a[1] * invc + bv0.y + BFHI(rv.x);
      hv[2] = a[2] * invc + bv0.z + BFLO(rv.y);
      hv[3] = a[3] * invc + bv0.w + BFHI(rv.y);
      hv[4] = a[4] * invc + bv1.x + BFLO(rv.z);
      hv[5] = a[5] * invc + bv1.y + BFHI(rv.z);
      hv[6] = a[6] * invc + bv1.z + BFLO(rv.w);
      hv[7] = a[7] * invc + bv1.w + BFHI(rv.w);
      *(float4*)&h[(size_t)node * 64 + f8 * 8]     = make_float4(hv[0], hv[1], hv[2], hv[3]);
      *(float4*)&h[(size_t)node * 64 + f8 * 8 + 4] = make_float4(hv[4], hv[5], hv[6], hv[7]);
#pragma unroll
      for (int j = 0; j < 8; ++j) { s[j] += hv[j]; q[j] += hv[j] * hv[j]; }
    }
  }

  // phase 5: BN partials
#pragma unroll
  for (int j = 0; j < 8; ++j) {
    s[j] += __shfl_xor(s[j], 8);  s[j] += __shfl_xor(s[j], 16); s[j] += __shfl_xor(s[j], 32);
    q[j] += __shfl_xor(q[j], 8);  q[j] += __shfl_xor(q[j], 16); q[j] += __shfl_xor(q[j], 32);
  }
  const int w = tid >> 6, lane = tid & 63;
  if (lane < 8) {
#pragma unroll
    for (int j = 0; j < 8; ++j) {
      bnWs[w][lane * 8 + j] = s[j];
      bnWq[w][lane * 8 + j] = q[j];
    }
  }
  __syncthreads();
  if (tid < 64) {
    float S = 0.f, Q = 0.f;
#pragma unroll
    for (int ww = 0; ww < 8; ++ww) { S += bnWs[ww][tid]; Q += bnWq[ww][tid]; }
    atomicAdd(&bnacc[tid], S);
    atomicAdd(&bnacc[64 + tid], Q);
  }
}

// ---------------------------------------------------------------------------
// k_layer2m (MFMA, BN-finalize fused): h' = relu(bn(h));
// zl = h'@W2_l^T (bf16); zr = h'@W2_r^T + b2 (f32)
// ---------------------------------------------------------------------------
__global__ __launch_bounds__(256) void k_layer2m(const float* __restrict__ h,
                                                 const float* __restrict__ W2l,
                                                 const float* __restrict__ W2r,
                                                 const float* __restrict__ b2,
                                                 const float* __restrict__ bnacc,
                                                 const float* __restrict__ gamma,
                                                 const float* __restrict__ beta,
                                                 ushort* __restrict__ zl,
                                                 float* __restrict__ zr) {
  __shared__ ushort hs[64 * 72];
  __shared__ ushort wss[32 * 72];
  __shared__ float sc[64], sh[64];
  const int tid = threadIdx.x;
  const int n0 = blockIdx.x * 64;

  if (tid < 64) {
    float mean = bnacc[tid] * (1.0f / NN);
    float var = bnacc[64 + tid] * (1.0f / NN) - mean * mean;
    float scv = gamma[tid] * rsqrtf(var + 1e-5f);
    sc[tid] = scv;
    sh[tid] = beta[tid] - mean * scv;
  }
  for (int i = tid; i < 32 * 16; i += 256) {
    int r = i >> 4, c = i & 15;
    const float* src = (r < 16) ? &W2l[r * 64 + c * 4] : &W2r[(r - 16) * 64 + c * 4];
    float4 v = *(const float4*)src;
    *(ushort4*)&wss[r * 72 + c * 4] = make_ushort4(f2bf(v.x), f2bf(v.y), f2bf(v.z), f2bf(v.w));
  }
  __syncthreads();

  for (int i = tid; i < 64 * 16; i += 256) {
    int r = i >> 4, c = i & 15;
    int n = n0 + r;
    float4 v = (n < NN) ? *(const float4*)&h[(size_t)n * 64 + c * 4]
                        : make_float4(0.f, 0.f, 0.f, 0.f);
    float4 o;
    o.x = fmaxf(v.x * sc[c * 4 + 0] + sh[c * 4 + 0], 0.f);
    o.y = fmaxf(v.y * sc[c * 4 + 1] + sh[c * 4 + 1], 0.f);
    o.z = fmaxf(v.z * sc[c * 4 + 2] + sh[c * 4 + 2], 0.f);
    o.w = fmaxf(v.w * sc[c * 4 + 3] + sh[c * 4 + 3], 0.f);
    *(ushort4*)&hs[r * 72 + c * 4] = make_ushort4(f2bf(o.x), f2bf(o.y), f2bf(o.z), f2bf(o.w));
  }
  __syncthreads();

  const int w = tid >> 6, l = tid & 63;
  const int col = l & 15, kb = l >> 4;

  f32x4 acc[2] = {(f32x4){0.f, 0.f, 0.f, 0.f}, (f32x4){0.f, 0.f, 0.f, 0.f}};
#pragma unroll
  for (int kc = 0; kc < 2; ++kc) {
    int koff = kc * 32 + kb * 8;
    bf16x8 a = *(const bf16x8*)&hs[(w * 16 + col) * 72 + koff];
    bf16x8 b0 = *(const bf16x8*)&wss[col * 72 + koff];
    bf16x8 b1v = *(const bf16x8*)&wss[(16 + col) * 72 + koff];
    acc[0] = __builtin_amdgcn_mfma_f32_16x16x32_bf16(a, b0, acc[0], 0, 0, 0);
    acc[1] = __builtin_amdgcn_mfma_f32_16x16x32_bf16(a, b1v, acc[1], 0, 0, 0);
  }

#pragma unroll
  for (int r = 0; r < 4; ++r) {
    int n = n0 + w * 16 + kb * 4 + r;
    if (n < NN) {
      zl[(size_t)n * 16 + col] = f2bf(acc[0][r]);
      zr[(size_t)n * 16 + col] = acc[1][r] + b2[col];
    }
  }
}

// ---------------------------------------------------------------------------
// k_agg2c: per bucket — edges already dst-sorted in ebuf (src list).
// 8-lane group per node, register accumulation; out = sums/deg + zr.
// ---------------------------------------------------------------------------
__global__ __launch_bounds__(512) void k_agg2c(const int* __restrict__ ebuf,
                                               const int* __restrict__ bstart,
                                               const int* __restrict__ hist,
                                               const ushort* __restrict__ zl,
                                               const float* __restrict__ zr,
                                               float* __restrict__ out) {
  __shared__ int elist[CAP];
  __shared__ int sd[128], deg[128], offx[128];
  const int tid = threadIdx.x;
  const int b = blockIdx.x;
  const int node0 = b << 7;
  const int nnode = min(NPB, NN - node0);
  const int kstart = bstart[b];
  const int T = min(bstart[b + 1] - kstart, CAP);

  for (int i = tid; i < T; i += 512) elist[i] = ebuf[kstart + i];
  if (tid < 128) {
    int d = (tid < nnode) ? hist[node0 + tid] : 0;
    deg[tid] = d;
    sd[tid] = d;
  }
  __syncthreads();
  for (int o = 1; o < 128; o <<= 1) {
    int v = (tid < 128 && tid >= o) ? sd[tid - o] : 0;
    __syncthreads();
    if (tid < 128) sd[tid] += v;
    __syncthreads();
  }
  if (tid < 128) offx[tid] = sd[tid] - deg[tid];
  __syncthreads();

  const int g = tid >> 3, f8 = tid & 7;
#pragma unroll
  for (int rep = 0; rep < 2; ++rep) {
    int dl = g + rep * 64;
    if (dl < nnode) {
      int st = offx[dl], d = deg[dl];
      float a0 = 0.f, a1 = 0.f;
      int k = st, ke = st + d;
      for (; k + 3 < ke; k += 4) {
        int s0 = elist[k], s1 = elist[k + 1], s2 = elist[k + 2], s3 = elist[k + 3];
        unsigned v0 = *(const unsigned*)&zl[(size_t)s0 * 16 + f8 * 2];
        unsigned v1 = *(const unsigned*)&zl[(size_t)s1 * 16 + f8 * 2];
        unsigned v2 = *(const unsigned*)&zl[(size_t)s2 * 16 + f8 * 2];
        unsigned v3 = *(const unsigned*)&zl[(size_t)s3 * 16 + f8 * 2];
        a0 += (BFLO(v0) + BFLO(v1)) + (BFLO(v2) + BFLO(v3));
        a1 += (BFHI(v0) + BFHI(v1)) + (BFHI(v2) + BFHI(v3));
      }
      for (; k < ke; ++k) {
        unsigned v0 = *(const unsigned*)&zl[(size_t)elist[k] * 16 + f8 * 2];
        a0 += BFLO(v0);
        a1 += BFHI(v0);
      }
      int node = node0 + dl;
      float invc = 1.0f / fmaxf((float)d, 1.0f);
      size_t base = (size_t)node * 16 + f8 * 2;
      out[base]     = a0 * invc + zr[base];
      out[base + 1] = a1 * invc + zr[base + 1];
    }
  }
}

// ---------------------------------------------------------------------------
extern "C" void kernel_launch(void* const* d_in, const int* in_sizes, int n_in,
                              void* d_out, int out_size, void* d_ws, size_t ws_size,
                              hipStream_t stream) {
  const float* x     = (const float*)d_in[0];
  const int*   ei    = (const int*)d_in[1];
  const float* W1l   = (const float*)d_in[2];
  const float* b1    = (const float*)d_in[3];
  const float* W1r   = (const float*)d_in[4];
  const float* gamma = (const float*)d_in[5];
  const float* beta  = (const float*)d_in[6];
  const float* W2l   = (const float*)d_in[7];
  const float* b2    = (const float*)d_in[8];
  const float* W2r   = (const float*)d_in[9];
  float* out = (float*)d_out;
  float* ws  = (float*)d_ws;

  float*  hbuf   = ws + OFF_H;
  ushort* yl     = (ushort*)(ws + OFF_YL);
  ushort* yr     = (ushort*)(ws + OFF_YR);
  ushort* zl     = (ushort*)(ws + OFF_YL);   // overlays yl (dead after agg1c)
  float*  zr     = ws + OFF_YR;              // overlays yr (dead after agg1c)
  int*    ebuf   = (int*)(ws + OFF_EBUF);
  int*    hist   = (int*)(ws + OFF_HIST);    // written by agg1c
  int*    bstart = (int*)(ws + OFF_BSTART);
  int*    bcurp  = (int*)(ws + OFF_BCURP);
  int*    bcntp  = (int*)(ws + OFF_BCNTP);
  float*  bnacc  = ws + OFF_BNACC;

  // bcntp (12512 i) and bnacc (128 f) are adjacent -> one memset
  hipMemsetAsync(bcntp, 0, (12512 + 128) * sizeof(int), stream);

  k_bcnt2<<<98, 1024, 0, stream>>>(ei, bcntp);
  k_bprep<<<1, 1024, 0, stream>>>(bcntp, bstart, bcurp);
  k_pg<<<NPART + NTILES, 512, 0, stream>>>(ei, bcurp, ebuf, x, W1l, W1r, yl, yr);
  k_agg1c<<<NBK, 512, 0, stream>>>(ebuf, bstart, hist, yl, yr, b1, hbuf, bnacc);
  k_layer2m<<<NTILES, 256, 0, stream>>>(hbuf, W2l, W2r, b2, bnacc, gamma, beta, zl, zr);
  k_agg2c<<<NBK, 512, 0, stream>>>(ebuf, bstart, hist, zl, zr, out);
}

// Round 16
// 137.958 us; speedup vs baseline: 7.5746x; 1.0630x over previous
//
#include <hip/hip_runtime.h>

#define NN 100000
#define NE 1600000
#define NPB 128                 // nodes per bucket
#define NBK 782                 // ceil(NN/128)
#define EPB 16384               // edges per partition block (>=84B chunks per bucket)
#define NPART 98                // ceil(NE/EPB)
#define NTILES 1563             // ceil(NN/64) gemm tiles
#define CAP 4096                // max edges per bucket in LDS

// workspace word offsets (ends 14,525,952 words = 58.1 MB)
#define OFF_H      0            // h f32 [N,64]
#define OFF_YL     6400000      // yl bf16 [N,64]; zl bf16 [N,16] overlays after agg1c
#define OFF_YR     9600000      // yr bf16 [N,64]; zr f32 [N,16] overlays after agg1c
#define OFF_EBUF   12800000     // packed edges int x 1.6M (raw -> sorted src in place)
#define OFF_HIST   14400000     // 100,000 i (degrees; written by agg1c, read by agg2c)
#define OFF_BSTART 14500000     // 783 i (incl sentinel)
#define OFF_BCURP  14500800     // 782*16 i (line-padded cursors)
#define OFF_BCNTP  14513312     // 782*16 i (line-padded counts; zeroed)
#define OFF_BNACC  14525824     // 128 f (zeroed)

typedef __attribute__((ext_vector_type(8))) short bf16x8;
typedef __attribute__((ext_vector_type(4))) float f32x4;

__device__ __forceinline__ ushort f2bf(float f) {   // RNE f32 -> bf16
  unsigned u = __float_as_uint(f);
  u += 0x7fffu + ((u >> 16) & 1);
  return (ushort)(u >> 16);
}
#define BFLO(u) __uint_as_float(((u) & 0xffffu) << 16)
#define BFHI(u) __uint_as_float((u) & 0xffff0000u)

// ---------------------------------------------------------------------------
// k_bcnt2: per-bucket edge counts (LDS histogram, then 1 padded global atomic
// per bucket per block)
// ---------------------------------------------------------------------------
__global__ __launch_bounds__(1024) void k_bcnt2(const int* __restrict__ ei,
                                                int* __restrict__ bcntp) {
  __shared__ int cnt[NBK];
  const int tid = threadIdx.x;
  for (int i = tid; i < NBK; i += 1024) cnt[i] = 0;
  __syncthreads();
  const int per = (NE + gridDim.x - 1) / gridDim.x;
  int e0 = blockIdx.x * per;
  int e1 = min(e0 + per, NE);
  for (int e = e0 + tid; e < e1; e += 1024)
    atomicAdd(&cnt[ei[NE + e] >> 7], 1);
  __syncthreads();
  for (int b = tid; b < NBK; b += 1024)
    if (cnt[b]) atomicAdd(&bcntp[b * 16], cnt[b]);
}

// ---------------------------------------------------------------------------
// k_bprep: exclusive scan of bcntp -> bstart (+sentinel), seed padded bcur
// ---------------------------------------------------------------------------
__global__ __launch_bounds__(1024) void k_bprep(const int* __restrict__ bcntp,
                                                int* __restrict__ bstart,
                                                int* __restrict__ bcurp) {
  __shared__ int sd[1024];
  int t = threadIdx.x;
  int v = (t < NBK) ? bcntp[t * 16] : 0;
  sd[t] = v;
  __syncthreads();
  for (int off = 1; off < 1024; off <<= 1) {
    int u = (t >= off) ? sd[t - off] : 0;
    __syncthreads();
    sd[t] += u;
    __syncthreads();
  }
  if (t < NBK) { int s = sd[t] - v; bstart[t] = s; bcurp[t * 16] = s; }
  if (t == 0) bstart[NBK] = NE;
}

// ---------------------------------------------------------------------------
// k_pg: FUSED partition + gemm12.
//   blocks [0, NPART): partition edges into bucket regions (packed src<<7|dl)
//   blocks [NPART, NPART+NTILES): MFMA gemm yl = x@W1l^T, yr = x@W1r^T
// Both are independent; they join at k_agg1c.
// ---------------------------------------------------------------------------
__global__ __launch_bounds__(512) void k_pg(const int* __restrict__ ei,
                                            int* __restrict__ bcurp,
                                            int* __restrict__ ebuf,
                                            const float* __restrict__ x,
                                            const float* __restrict__ W1l,
                                            const float* __restrict__ W1r,
                                            ushort* __restrict__ yl,
                                            ushort* __restrict__ yr) {
  __shared__ ushort smem[64 * 136 + 128 * 136];   // 52.2 KB
  const int tid = threadIdx.x;

  if (blockIdx.x < NPART) {
    // ---- partition branch ----
    int* cnt = (int*)smem;
    int* gstart = cnt + NBK;
    int* cur = gstart + NBK;
    int e0 = blockIdx.x * EPB;
    int e1 = min(e0 + EPB, NE);
    for (int i = tid; i < NBK; i += 512) cnt[i] = 0;
    __syncthreads();
    for (int e = e0 + tid; e < e1; e += 512)
      atomicAdd(&cnt[ei[NE + e] >> 7], 1);
    __syncthreads();
    for (int b = tid; b < NBK; b += 512) {
      int c = cnt[b];
      gstart[b] = c ? atomicAdd(&bcurp[b * 16], c) : 0;
      cur[b] = 0;
    }
    __syncthreads();
    for (int e = e0 + tid; e < e1; e += 512) {
      int s = ei[e], t = ei[NE + e];
      int b = t >> 7;
      int r = atomicAdd(&cur[b], 1);
      ebuf[gstart[b] + r] = (s << 7) | (t & 127);
    }
    return;
  }

  // ---- gemm branch (8 waves, wave w owns out-tile w) ----
  ushort* xs = smem;               // 64 x 136
  ushort* wss = smem + 64 * 136;   // 128 x 136
  const int n0 = (blockIdx.x - NPART) * 64;

  for (int i = tid; i < 64 * 32; i += 512) {
    int r = i >> 5, c = i & 31;
    int n = n0 + r;
    float4 v = (n < NN) ? *(const float4*)&x[(size_t)n * 128 + c * 4]
                        : make_float4(0.f, 0.f, 0.f, 0.f);
    *(ushort4*)&xs[r * 136 + c * 4] = make_ushort4(f2bf(v.x), f2bf(v.y), f2bf(v.z), f2bf(v.w));
  }
  for (int i = tid; i < 128 * 32; i += 512) {
    int r = i >> 5, c = i & 31;
    const float* src = (r < 64) ? &W1l[r * 128 + c * 4] : &W1r[(r - 64) * 128 + c * 4];
    float4 v = *(const float4*)src;
    *(ushort4*)&wss[r * 136 + c * 4] = make_ushort4(f2bf(v.x), f2bf(v.y), f2bf(v.z), f2bf(v.w));
  }
  __syncthreads();

  const int w = tid >> 6, l = tid & 63;
  const int col = l & 15, kb = l >> 4;

  f32x4 acc[4];
#pragma unroll
  for (int nt = 0; nt < 4; ++nt) acc[nt] = (f32x4){0.f, 0.f, 0.f, 0.f};

#pragma unroll
  for (int kc = 0; kc < 4; ++kc) {
    int koff = kc * 32 + kb * 8;
    bf16x8 a[4];
#pragma unroll
    for (int nt = 0; nt < 4; ++nt)
      a[nt] = *(const bf16x8*)&xs[(nt * 16 + col) * 136 + koff];
    bf16x8 b = *(const bf16x8*)&wss[(w * 16 + col) * 136 + koff];
#pragma unroll
    for (int nt = 0; nt < 4; ++nt)
      acc[nt] = __builtin_amdgcn_mfma_f32_16x16x32_bf16(a[nt], b, acc[nt], 0, 0, 0);
  }

  const int outc = w * 16 + col;
#pragma unroll
  for (int nt = 0; nt < 4; ++nt) {
#pragma unroll
    for (int r = 0; r < 4; ++r) {
      int n = n0 + nt * 16 + kb * 4 + r;
      if (n < NN) {
        ushort v = f2bf(acc[nt][r]);
        if (outc < 64) yl[(size_t)n * 64 + outc] = v;
        else           yr[(size_t)n * 64 + (outc - 64)] = v;
      }
    }
  }
}

// ---------------------------------------------------------------------------
// k_agg1c: per bucket — LDS degree count, counting-sort by dst, 8-lane groups
// accumulate contiguous edge lists in registers (unroll-4 gathers).
// Writes sorted src list back to ebuf and degrees to hist.
// h = sums/deg + b1 + yr; BN partials via shfl reduce.
// ---------------------------------------------------------------------------
__global__ __launch_bounds__(512) void k_agg1c(int* __restrict__ ebuf,
                                               const int* __restrict__ bstart,
                                               int* __restrict__ hist,
                                               const ushort* __restrict__ yl,
                                               const ushort* __restrict__ yr,
                                               const float* __restrict__ b1,
                                               float* __restrict__ h,
                                               float* __restrict__ bnacc) {
  __shared__ int raw[CAP];
  __shared__ int srt[CAP];
  __shared__ int sd[128], deg[128], offx[128], cursor[128];
  __shared__ float bnWs[8][64], bnWq[8][64];
  const int tid = threadIdx.x;
  const int b = blockIdx.x;
  const int node0 = b << 7;
  const int nnode = min(NPB, NN - node0);
  const int kstart = bstart[b];
  const int T = min(bstart[b + 1] - kstart, CAP);

  // phase 1: stage raw edges + LDS degree count
  if (tid < 128) deg[tid] = 0;
  __syncthreads();
  for (int i = tid; i < T; i += 512) {
    int e = ebuf[kstart + i];
    raw[i] = e;
    atomicAdd(&deg[e & 127], 1);
  }
  __syncthreads();
  if (tid < 128) sd[tid] = deg[tid];
  __syncthreads();
  for (int o = 1; o < 128; o <<= 1) {
    int v = (tid < 128 && tid >= o) ? sd[tid - o] : 0;
    __syncthreads();
    if (tid < 128) sd[tid] += v;
    __syncthreads();
  }
  if (tid < 128) {
    int s = sd[tid] - deg[tid];
    offx[tid] = s;
    cursor[tid] = s;
    if (tid < nnode) hist[node0 + tid] = deg[tid];
  }
  __syncthreads();

  // phase 2: counting sort by dst
  for (int i = tid; i < T; i += 512) {
    int e = raw[i];
    int slot = atomicAdd(&cursor[e & 127], 1);
    srt[slot] = e >> 7;
  }
  __syncthreads();

  // phase 3: write sorted src list back (for agg2c)
  for (int i = tid; i < T; i += 512) ebuf[kstart + i] = srt[i];

  // phase 4: register accumulation, 8-lane group per node, unroll-4
  const int g = tid >> 3, f8 = tid & 7;
  float s[8] = {}, q[8] = {};
#pragma unroll
  for (int rep = 0; rep < 2; ++rep) {
    int dl = g + rep * 64;
    if (dl < nnode) {
      int st = offx[dl], d = deg[dl];
      float a[8] = {};
      int k = st, ke = st + d;
      for (; k + 3 < ke; k += 4) {
        int s0 = srt[k], s1 = srt[k + 1], s2 = srt[k + 2], s3 = srt[k + 3];
        uint4 v0 = *(const uint4*)&yl[(size_t)s0 * 64 + f8 * 8];
        uint4 v1 = *(const uint4*)&yl[(size_t)s1 * 64 + f8 * 8];
        uint4 v2 = *(const uint4*)&yl[(size_t)s2 * 64 + f8 * 8];
        uint4 v3 = *(const uint4*)&yl[(size_t)s3 * 64 + f8 * 8];
        a[0] += (BFLO(v0.x) + BFLO(v1.x)) + (BFLO(v2.x) + BFLO(v3.x));
        a[1] += (BFHI(v0.x) + BFHI(v1.x)) + (BFHI(v2.x) + BFHI(v3.x));
        a[2] += (BFLO(v0.y) + BFLO(v1.y)) + (BFLO(v2.y) + BFLO(v3.y));
        a[3] += (BFHI(v0.y) + BFHI(v1.y)) + (BFHI(v2.y) + BFHI(v3.y));
        a[4] += (BFLO(v0.z) + BFLO(v1.z)) + (BFLO(v2.z) + BFLO(v3.z));
        a[5] += (BFHI(v0.z) + BFHI(v1.z)) + (BFHI(v2.z) + BFHI(v3.z));
        a[6] += (BFLO(v0.w) + BFLO(v1.w)) + (BFLO(v2.w) + BFLO(v3.w));
        a[7] += (BFHI(v0.w) + BFHI(v1.w)) + (BFHI(v2.w) + BFHI(v3.w));
      }
      for (; k < ke; ++k) {
        int s0 = srt[k];
        uint4 v0 = *(const uint4*)&yl[(size_t)s0 * 64 + f8 * 8];
        a[0] += BFLO(v0.x); a[1] += BFHI(v0.x);
        a[2] += BFLO(v0.y); a[3] += BFHI(v0.y);
        a[4] += BFLO(v0.z); a[5] += BFHI(v0.z);
        a[6] += BFLO(v0.w); a[7] += BFHI(v0.w);
      }
      int node = node0 + dl;
      float invc = 1.0f / fmaxf((float)d, 1.0f);
      uint4 rv = *(const uint4*)&yr[(size_t)node * 64 + f8 * 8];
      float4 bv0 = *(const float4*)&b1[f8 * 8];
      float4 bv1 = *(const float4*)&b1[f8 * 8 + 4];
      float hv[8];
      hv[0] = a[0] * invc + bv0.x + BFLO(rv.x);
      hv[1] = a[1] * invc + bv0.y + BFHI(rv.x);
      hv[2] = a[2] * invc + bv0.z + BFLO(rv.y);
      hv[3] = a[3] * invc + bv0.w + BFHI(rv.y);
      hv[4] = a[4] * invc + bv1.x + BFLO(rv.z);
      hv[5] = a[5] * invc + bv1.y + BFHI(rv.z);
      hv[6] = a[6] * invc + bv1.z + BFLO(rv.w);
      hv[7] = a[7] * invc + bv1.w + BFHI(rv.w);
      *(float4*)&h[(size_t)node * 64 + f8 * 8]     = make_float4(hv[0], hv[1], hv[2], hv[3]);
      *(float4*)&h[(size_t)node * 64 + f8 * 8 + 4] = make_float4(hv[4], hv[5], hv[6], hv[7]);
#pragma unroll
      for (int j = 0; j < 8; ++j) { s[j] += hv[j]; q[j] += hv[j] * hv[j]; }
    }
  }

  // phase 5: BN partials
#pragma unroll
  for (int j = 0; j < 8; ++j) {
    s[j] += __shfl_xor(s[j], 8);  s[j] += __shfl_xor(s[j], 16); s[j] += __shfl_xor(s[j], 32);
    q[j] += __shfl_xor(q[j], 8);  q[j] += __shfl_xor(q[j], 16); q[j] += __shfl_xor(q[j], 32);
  }
  const int w = tid >> 6, lane = tid & 63;
  if (lane < 8) {
#pragma unroll
    for (int j = 0; j < 8; ++j) {
      bnWs[w][lane * 8 + j] = s[j];
      bnWq[w][lane * 8 + j] = q[j];
    }
  }
  __syncthreads();
  if (tid < 64) {
    float S = 0.f, Q = 0.f;
#pragma unroll
    for (int ww = 0; ww < 8; ++ww) { S += bnWs[ww][tid]; Q += bnWq[ww][tid]; }
    atomicAdd(&bnacc[tid], S);
    atomicAdd(&bnacc[64 + tid], Q);
  }
}

// ---------------------------------------------------------------------------
// k_layer2m (MFMA, BN-finalize fused): h' = relu(bn(h));
// zl = h'@W2_l^T (bf16); zr = h'@W2_r^T + b2 (f32)
// ---------------------------------------------------------------------------
__global__ __launch_bounds__(256) void k_layer2m(const float* __restrict__ h,
                                                 const float* __restrict__ W2l,
                                                 const float* __restrict__ W2r,
                                                 const float* __restrict__ b2,
                                                 const float* __restrict__ bnacc,
                                                 const float* __restrict__ gamma,
                                                 const float* __restrict__ beta,
                                                 ushort* __restrict__ zl,
                                                 float* __restrict__ zr) {
  __shared__ ushort hs[64 * 72];
  __shared__ ushort wss[32 * 72];
  __shared__ float sc[64], sh[64];
  const int tid = threadIdx.x;
  const int n0 = blockIdx.x * 64;

  if (tid < 64) {
    float mean = bnacc[tid] * (1.0f / NN);
    float var = bnacc[64 + tid] * (1.0f / NN) - mean * mean;
    float scv = gamma[tid] * rsqrtf(var + 1e-5f);
    sc[tid] = scv;
    sh[tid] = beta[tid] - mean * scv;
  }
  for (int i = tid; i < 32 * 16; i += 256) {
    int r = i >> 4, c = i & 15;
    const float* src = (r < 16) ? &W2l[r * 64 + c * 4] : &W2r[(r - 16) * 64 + c * 4];
    float4 v = *(const float4*)src;
    *(ushort4*)&wss[r * 72 + c * 4] = make_ushort4(f2bf(v.x), f2bf(v.y), f2bf(v.z), f2bf(v.w));
  }
  __syncthreads();

  for (int i = tid; i < 64 * 16; i += 256) {
    int r = i >> 4, c = i & 15;
    int n = n0 + r;
    float4 v = (n < NN) ? *(const float4*)&h[(size_t)n * 64 + c * 4]
                        : make_float4(0.f, 0.f, 0.f, 0.f);
    float4 o;
    o.x = fmaxf(v.x * sc[c * 4 + 0] + sh[c * 4 + 0], 0.f);
    o.y = fmaxf(v.y * sc[c * 4 + 1] + sh[c * 4 + 1], 0.f);
    o.z = fmaxf(v.z * sc[c * 4 + 2] + sh[c * 4 + 2], 0.f);
    o.w = fmaxf(v.w * sc[c * 4 + 3] + sh[c * 4 + 3], 0.f);
    *(ushort4*)&hs[r * 72 + c * 4] = make_ushort4(f2bf(o.x), f2bf(o.y), f2bf(o.z), f2bf(o.w));
  }
  __syncthreads();

  const int w = tid >> 6, l = tid & 63;
  const int col = l & 15, kb = l >> 4;

  f32x4 acc[2] = {(f32x4){0.f, 0.f, 0.f, 0.f}, (f32x4){0.f, 0.f, 0.f, 0.f}};
#pragma unroll
  for (int kc = 0; kc < 2; ++kc) {
    int koff = kc * 32 + kb * 8;
    bf16x8 a = *(const bf16x8*)&hs[(w * 16 + col) * 72 + koff];
    bf16x8 b0 = *(const bf16x8*)&wss[col * 72 + koff];
    bf16x8 b1v = *(const bf16x8*)&wss[(16 + col) * 72 + koff];
    acc[0] = __builtin_amdgcn_mfma_f32_16x16x32_bf16(a, b0, acc[0], 0, 0, 0);
    acc[1] = __builtin_amdgcn_mfma_f32_16x16x32_bf16(a, b1v, acc[1], 0, 0, 0);
  }

#pragma unroll
  for (int r = 0; r < 4; ++r) {
    int n = n0 + w * 16 + kb * 4 + r;
    if (n < NN) {
      zl[(size_t)n * 16 + col] = f2bf(acc[0][r]);
      zr[(size_t)n * 16 + col] = acc[1][r] + b2[col];
    }
  }
}

// ---------------------------------------------------------------------------
// k_agg2c: per bucket — edges already dst-sorted in ebuf (src list).
// 8-lane group per node, register accumulation; out = sums/deg + zr.
// ---------------------------------------------------------------------------
__global__ __launch_bounds__(512) void k_agg2c(const int* __restrict__ ebuf,
                                               const int* __restrict__ bstart,
                                               const int* __restrict__ hist,
                                               const ushort* __restrict__ zl,
                                               const float* __restrict__ zr,
                                               float* __restrict__ out) {
  __shared__ int elist[CAP];
  __shared__ int sd[128], deg[128], offx[128];
  const int tid = threadIdx.x;
  const int b = blockIdx.x;
  const int node0 = b << 7;
  const int nnode = min(NPB, NN - node0);
  const int kstart = bstart[b];
  const int T = min(bstart[b + 1] - kstart, CAP);

  for (int i = tid; i < T; i += 512) elist[i] = ebuf[kstart + i];
  if (tid < 128) {
    int d = (tid < nnode) ? hist[node0 + tid] : 0;
    deg[tid] = d;
    sd[tid] = d;
  }
  __syncthreads();
  for (int o = 1; o < 128; o <<= 1) {
    int v = (tid < 128 && tid >= o) ? sd[tid - o] : 0;
    __syncthreads();
    if (tid < 128) sd[tid] += v;
    __syncthreads();
  }
  if (tid < 128) offx[tid] = sd[tid] - deg[tid];
  __syncthreads();

  const int g = tid >> 3, f8 = tid & 7;
#pragma unroll
  for (int rep = 0; rep < 2; ++rep) {
    int dl = g + rep * 64;
    if (dl < nnode) {
      int st = offx[dl], d = deg[dl];
      float a0 = 0.f, a1 = 0.f;
      int k = st, ke = st + d;
      for (; k + 3 < ke; k += 4) {
        int s0 = elist[k], s1 = elist[k + 1], s2 = elist[k + 2], s3 = elist[k + 3];
        unsigned v0 = *(const unsigned*)&zl[(size_t)s0 * 16 + f8 * 2];
        unsigned v1 = *(const unsigned*)&zl[(size_t)s1 * 16 + f8 * 2];
        unsigned v2 = *(const unsigned*)&zl[(size_t)s2 * 16 + f8 * 2];
        unsigned v3 = *(const unsigned*)&zl[(size_t)s3 * 16 + f8 * 2];
        a0 += (BFLO(v0) + BFLO(v1)) + (BFLO(v2) + BFLO(v3));
        a1 += (BFHI(v0) + BFHI(v1)) + (BFHI(v2) + BFHI(v3));
      }
      for (; k < ke; ++k) {
        unsigned v0 = *(const unsigned*)&zl[(size_t)elist[k] * 16 + f8 * 2];
        a0 += BFLO(v0);
        a1 += BFHI(v0);
      }
      int node = node0 + dl;
      float invc = 1.0f / fmaxf((float)d, 1.0f);
      size_t base = (size_t)node * 16 + f8 * 2;
      out[base]     = a0 * invc + zr[base];
      out[base + 1] = a1 * invc + zr[base + 1];
    }
  }
}

// ---------------------------------------------------------------------------
extern "C" void kernel_launch(void* const* d_in, const int* in_sizes, int n_in,
                              void* d_out, int out_size, void* d_ws, size_t ws_size,
                              hipStream_t stream) {
  const float* x     = (const float*)d_in[0];
  const int*   ei    = (const int*)d_in[1];
  const float* W1l   = (const float*)d_in[2];
  const float* b1    = (const float*)d_in[3];
  const float* W1r   = (const float*)d_in[4];
  const float* gamma = (const float*)d_in[5];
  const float* beta  = (const float*)d_in[6];
  const float* W2l   = (const float*)d_in[7];
  const float* b2    = (const float*)d_in[8];
  const float* W2r   = (const float*)d_in[9];
  float* out = (float*)d_out;
  float* ws  = (float*)d_ws;

  float*  hbuf   = ws + OFF_H;
  ushort* yl     = (ushort*)(ws + OFF_YL);
  ushort* yr     = (ushort*)(ws + OFF_YR);
  ushort* zl     = (ushort*)(ws + OFF_YL);   // overlays yl (dead after agg1c)
  float*  zr     = ws + OFF_YR;              // overlays yr (dead after agg1c)
  int*    ebuf   = (int*)(ws + OFF_EBUF);
  int*    hist   = (int*)(ws + OFF_HIST);    // written by agg1c
  int*    bstart = (int*)(ws + OFF_BSTART);
  int*    bcurp  = (int*)(ws + OFF_BCURP);
  int*    bcntp  = (int*)(ws + OFF_BCNTP);
  float*  bnacc  = ws + OFF_BNACC;

  // bcntp (12512 i) and bnacc (128 f) are adjacent -> one memset
  hipMemsetAsync(bcntp, 0, (12512 + 128) * sizeof(int), stream);

  k_bcnt2<<<98, 1024, 0, stream>>>(ei, bcntp);
  k_bprep<<<1, 1024, 0, stream>>>(bcntp, bstart, bcurp);
  k_pg<<<NPART + NTILES, 512, 0, stream>>>(ei, bcurp, ebuf, x, W1l, W1r, yl, yr);
  k_agg1c<<<NBK, 512, 0, stream>>>(ebuf, bstart, hist, yl, yr, b1, hbuf, bnacc);
  k_layer2m<<<NTILES, 256, 0, stream>>>(hbuf, W2l, W2r, b2, bnacc, gamma, beta, zl, zr);
  k_agg2c<<<NBK, 512, 0, stream>>>(ebuf, bstart, hist, zl, zr, out);
}